// Round 13
// baseline (427.004 us; speedup 1.0000x reference)
//
#include <hip/hip_runtime.h>

// ---------------------------------------------------------------------------
// MR_GNN: 2x (RGCN + GroupEnhance) + linear head.
// R14 (resubmit; R12-round bench was an infra failure -- container acquire
// died twice, no kernel error/absmax/profile, same signature as R5 which
// passed unchanged on resubmit):
// node_gemm<0> was the top cost (45us x2, occupancy 20%, VALU 38%) -- 5
// sequential stage->barrier->compute chunks expose global latency, and the
// k-loop's 4 scalar As reads put LDS on the critical path.
// (a) software pipeline: prefetch chunk c+1 A/B into registers during chunk
//     c's compute (same barrier count, latency hidden under k-loop);
// (b) transposed A-tile AsT[k][row] (pad 68): k-loop = 2x ds_read_b128
//     broadcast, conflict-free;
// (c) MODE0 A-operand reads the bf16 shadow (xb/gb) -> uniform ushort4
//     prefetch, -6.4MB fetch.
// MODE1/3 get the AsT k-loop; MODE3 mini-GEMM transposed too. Gathers, CSR
// build, bf16 shadow scheme unchanged from R13 (400us).
// ---------------------------------------------------------------------------

#define PART_EPB 2048  // edges per partition/hist block (256 thr x 8)

// ---- CSR build, pass A1: per-bucket edge counts (bucket = dst >> 8) ----
__global__ __launch_bounds__(256) void bucket_hist(const int* __restrict__ ei,
                                                   int* __restrict__ bcnt,
                                                   int E, int NB) {
    __shared__ int h[1024];
    for (int i = threadIdx.x; i < 1024; i += 256) h[i] = 0;
    __syncthreads();
    int base = blockIdx.x * PART_EPB;
#pragma unroll
    for (int k = 0; k < PART_EPB / 256; ++k) {
        int e = base + k * 256 + threadIdx.x;
        if (e < E) atomicAdd(&h[ei[E + e] >> 8], 1);
    }
    __syncthreads();
    for (int i = threadIdx.x; i < NB; i += 256)
        if (h[i]) atomicAdd(&bcnt[i], h[i]);
}

// ---- pass A-scan: exclusive scan of NB (<=1024) bucket counts ----
__global__ __launch_bounds__(1024) void bucket_scan(const int* __restrict__ bcnt,
                                                    int* __restrict__ bofs,
                                                    int* __restrict__ bcur,
                                                    int NB, int E) {
    __shared__ int lds[1024];
    int tid = threadIdx.x;
    int v = (tid < NB) ? bcnt[tid] : 0;
    lds[tid] = v;
    __syncthreads();
    int acc = v;
    for (int off = 1; off < 1024; off <<= 1) {
        int t = (tid >= off) ? lds[tid - off] : 0;
        __syncthreads();
        acc += t;
        lds[tid] = acc;
        __syncthreads();
    }
    int excl = acc - v;
    if (tid < NB) { bofs[tid] = excl; bcur[tid] = excl; }
    if (tid == 0) bofs[NB] = E;
}

// ---- pass A2: block-aggregated partition into bucket streams ----
__global__ __launch_bounds__(256) void partition(const int* __restrict__ ei,
                                                 const int* __restrict__ et,
                                                 const float* __restrict__ ew,
                                                 int* __restrict__ gcur,
                                                 int2* __restrict__ recA,
                                                 int* __restrict__ recB,
                                                 int E, int NB) {
    __shared__ int hist[1024];
    __shared__ int base[1024];
    const int tid = threadIdx.x;
    const int blockBase = blockIdx.x * PART_EPB;
    for (int i = tid; i < 1024; i += 256) hist[i] = 0;
    __syncthreads();
#pragma unroll
    for (int k = 0; k < PART_EPB / 256; ++k) {
        int e = blockBase + k * 256 + tid;
        if (e < E) atomicAdd(&hist[ei[E + e] >> 8], 1);
    }
    __syncthreads();
    for (int i = tid; i < NB; i += 256) {
        int h = hist[i];
        base[i] = h ? atomicAdd(&gcur[i], h) : 0;
    }
    __syncthreads();
    for (int i = tid; i < 1024; i += 256) hist[i] = 0;  // reuse as run cursor
    __syncthreads();
#pragma unroll
    for (int k = 0; k < PART_EPB / 256; ++k) {
        int e = blockBase + k * 256 + tid;
        if (e >= E) continue;
        int dst = ei[E + e];
        int b = dst >> 8;
        int pos = base[b] + atomicAdd(&hist[b], 1);
        recA[pos] = make_int2(ei[e], __float_as_int(ew[e]));
        recB[pos] = dst * 4 + et[e];
    }
}

// ---- pass B: per-bucket (node,rel) hist + scan in LDS, write rp2 + pw ----
__global__ __launch_bounds__(256) void bucket_fill(
    const int2* __restrict__ recA, const int* __restrict__ recB,
    const int* __restrict__ bofs, int* __restrict__ rp2, int2* __restrict__ pw,
    int N) {
    __shared__ int cnt[1024];
    __shared__ int cur[1024];
    __shared__ int wsum[4];
    const int b = blockIdx.x;
    const int tid = threadIdx.x;
    const int beg = bofs[b], end = bofs[b + 1];
    const int rebase = b << 10;  // base index in (dst*4+rel) space
    for (int j = 0; j < 4; ++j) cnt[tid * 4 + j] = 0;
    __syncthreads();
    for (int i = beg + tid; i < end; i += 256)
        atomicAdd(&cnt[recB[i] - rebase], 1);
    __syncthreads();
    int v[4];
    int s = 0;
#pragma unroll
    for (int j = 0; j < 4; ++j) { v[j] = cnt[tid * 4 + j]; s += v[j]; }
    int lane = tid & 63, wid = tid >> 6;
    int ws = s;
#pragma unroll
    for (int off = 1; off < 64; off <<= 1) {
        int t = __shfl_up(ws, off);
        if (lane >= off) ws += t;
    }
    if (lane == 63) wsum[wid] = ws;
    __syncthreads();
    int wb = 0;
    for (int w = 0; w < wid; ++w) wb += wsum[w];
    int run = beg + wb + ws - s;
#pragma unroll
    for (int j = 0; j < 4; ++j) {
        int idx = rebase + tid * 4 + j;
        if (idx <= 4 * N) rp2[idx] = run;
        cur[tid * 4 + j] = run;
        run += v[j];
    }
    __syncthreads();
    for (int i = beg + tid; i < end; i += 256) {
        int l = recB[i] - rebase;
        int p = atomicAdd(&cur[l], 1);
        pw[p] = recA[i];
    }
}

__device__ __forceinline__ float4 quad_reduce(float4 a) {
#pragma unroll
    for (int off = 16; off < 64; off <<= 1) {
        a.x += __shfl_xor(a.x, off);
        a.y += __shfl_xor(a.y, off);
        a.z += __shfl_xor(a.z, off);
        a.w += __shfl_xor(a.w, off);
    }
    return a;
}

__device__ __forceinline__ void fma4(float4& a, float w, const float4& x) {
    a.x += w * x.x; a.y += w * x.y; a.z += w * x.z; a.w += w * x.w;
}

__device__ __forceinline__ unsigned short f2bf(float f) {
    unsigned u = __float_as_uint(f);
    unsigned r = u + 0x7fffu + ((u >> 16) & 1u);  // round-to-nearest-even
    return (unsigned short)(r >> 16);
}

__device__ __forceinline__ float bf2f(unsigned short h) {
    return __uint_as_float(((unsigned)h) << 16);
}

__device__ __forceinline__ float4 bf2f4(ushort4 h) {
    return make_float4(bf2f(h.x), bf2f(h.y), bf2f(h.z), bf2f(h.w));
}

// ---- fp32 -> bf16 table cast (for x; sequential, ~2us) ----
__global__ __launch_bounds__(256) void cast_bf16(const float* __restrict__ in,
                                                 unsigned short* __restrict__ out,
                                                 int n4) {
    int i = blockIdx.x * 256 + threadIdx.x;
    if (i >= n4) return;
    float4 v = reinterpret_cast<const float4*>(in)[i];
    reinterpret_cast<ushort4*>(out)[i] =
        make_ushort4(f2bf(v.x), f2bf(v.y), f2bf(v.z), f2bf(v.w));
}

// ---------------------------------------------------------------------------
// Unified-range gather (R7 structure; bf16 input table; proven in R13).
// REL=1: masked per-relation accumulators -> bf16 out (ushort N x 256).
// REL=0: 4 chains summed -> fp32 out (float N x 64).
// ---------------------------------------------------------------------------
template <int REL>
__global__ __launch_bounds__(256) void gather_k(
    const unsigned short* __restrict__ Xb, const int* __restrict__ rp2,
    const int2* __restrict__ pw, void* __restrict__ outp, int N) {
    int node = blockIdx.x * 4 + (threadIdx.x >> 6);
    if (node >= N) return;
    int lane = threadIdx.x & 63;
    int q = lane >> 4, m = lane & 15;
    const int4 sv = *reinterpret_cast<const int4*>(rp2 + node * 4);
    const int s0 = sv.x, s1 = sv.y, s2 = sv.z, s3 = sv.w;
    const int s4 = rp2[node * 4 + 4];
    float4 A0 = make_float4(0.f, 0.f, 0.f, 0.f);
    float4 A1 = make_float4(0.f, 0.f, 0.f, 0.f);
    float4 A2 = make_float4(0.f, 0.f, 0.f, 0.f);
    float4 A3 = make_float4(0.f, 0.f, 0.f, 0.f);

    auto accum = [&](int idx, int slot, int2 e, const float4& xv) {
        float w = __int_as_float(e.y);
        if (REL) {
            fma4(A0, (idx < s1) ? w : 0.f, xv);
            fma4(A1, (idx >= s1 && idx < s2) ? w : 0.f, xv);
            fma4(A2, (idx >= s2 && idx < s3) ? w : 0.f, xv);
            fma4(A3, (idx >= s3) ? w : 0.f, xv);
        } else {
            if (slot == 0) fma4(A0, w, xv);
            else if (slot == 1) fma4(A1, w, xv);
            else if (slot == 2) fma4(A2, w, xv);
            else fma4(A3, w, xv);
        }
    };

    int i = s0 + q;
    for (; i + 12 < s4; i += 16) {  // 4 gathers in flight
        int2 e0 = pw[i];
        int2 e1 = pw[i + 4];
        int2 e2 = pw[i + 8];
        int2 e3 = pw[i + 12];
        ushort4 h0 = *reinterpret_cast<const ushort4*>(Xb + (size_t)e0.x * 64 + m * 4);
        ushort4 h1 = *reinterpret_cast<const ushort4*>(Xb + (size_t)e1.x * 64 + m * 4);
        ushort4 h2 = *reinterpret_cast<const ushort4*>(Xb + (size_t)e2.x * 64 + m * 4);
        ushort4 h3 = *reinterpret_cast<const ushort4*>(Xb + (size_t)e3.x * 64 + m * 4);
        accum(i, 0, e0, bf2f4(h0));
        accum(i + 4, 1, e1, bf2f4(h1));
        accum(i + 8, 2, e2, bf2f4(h2));
        accum(i + 12, 3, e3, bf2f4(h3));
    }
    for (; i + 4 < s4; i += 8) {  // 2 in flight
        int2 e0 = pw[i];
        int2 e1 = pw[i + 4];
        ushort4 h0 = *reinterpret_cast<const ushort4*>(Xb + (size_t)e0.x * 64 + m * 4);
        ushort4 h1 = *reinterpret_cast<const ushort4*>(Xb + (size_t)e1.x * 64 + m * 4);
        accum(i, 0, e0, bf2f4(h0));
        accum(i + 4, 1, e1, bf2f4(h1));
    }
    if (i < s4) {
        int2 e0 = pw[i];
        ushort4 h0 = *reinterpret_cast<const ushort4*>(Xb + (size_t)e0.x * 64 + m * 4);
        accum(i, 0, e0, bf2f4(h0));
    }

    if (REL) {
        A0 = quad_reduce(A0);
        A1 = quad_reduce(A1);
        A2 = quad_reduce(A2);
        A3 = quad_reduce(A3);
        float4 o = (q == 0) ? A0 : (q == 1) ? A1 : (q == 2) ? A2 : A3;
        ushort4 h = make_ushort4(f2bf(o.x), f2bf(o.y), f2bf(o.z), f2bf(o.w));
        *reinterpret_cast<ushort4*>((unsigned short*)outp +
                                    (size_t)node * 256 + q * 64 + m * 4) = h;
    } else {
        A0.x += A1.x + A2.x + A3.x;
        A0.y += A1.y + A2.y + A3.y;
        A0.z += A1.z + A2.z + A3.z;
        A0.w += A1.w + A2.w + A3.w;
        A0 = quad_reduce(A0);
        if (q == 0)
            *reinterpret_cast<float4*>((float*)outp + (size_t)node * 64 + m * 4) = A0;
    }
}

// ---------------------------------------------------------------------------
// Node-side tiled GEMM with transposed A-tile (AsT[k][row], pad 68) and,
// for MODE 0, a register-prefetch pipeline over the 5 k-chunks.
// MODE 0 (rgcn):  OUT = relu((Xb0@B0 + AGGh@B1) / deg)  (A operands bf16)
//                 also writes OUTb (bf16 shadow).          OUT: N x 64
// MODE 1 (group): OUT = Xf + alpha*((AGGf@B0)/deg + bias); also OUTb.
//                                                           OUT: N x 64
// MODE 3 (group+head): g = Xf + alpha*((AGGf@B0)/deg + bias);
//                      OUT = g@B1 + bias2                   OUT: N x 32
// ---------------------------------------------------------------------------
template <int MODE>
__global__ __launch_bounds__(256) void node_gemm(
    const float* __restrict__ Xf, const float* __restrict__ AGGf,
    const unsigned short* __restrict__ Xb0, const unsigned short* __restrict__ AGGh,
    const float* __restrict__ B0, const float* __restrict__ B1,
    const float* __restrict__ bias, const float* __restrict__ bias2,
    const float* __restrict__ alphap, const int* __restrict__ rp2,
    float* __restrict__ OUT, unsigned short* __restrict__ OUTb, int N) {
    __shared__ float AsT[64][68];   // AsT[k][row] = A[row][k]
    __shared__ float Bs[64][64];
    const int tid = threadIdx.x;
    const int tx = tid & 15, ty = tid >> 4;
    const int row0 = blockIdx.x * 64;
    float acc[4][4] = {};

    if (MODE == 0) {
        ushort4 ph[4];
        float4 pbv[4];
        // prologue: prefetch chunk 0 (A = Xb0 bf16, B = B0)
#pragma unroll
        for (int q = 0; q < 4; ++q) {
            int f = q * 256 + tid;
            int r = f >> 4, c4 = (f & 15) << 2;
            int vr = row0 + r;
            ph[q] = make_ushort4(0, 0, 0, 0);
            if (vr < N)
                ph[q] = *reinterpret_cast<const ushort4*>(Xb0 + (size_t)vr * 64 + c4);
            pbv[q] = *reinterpret_cast<const float4*>(B0 + (size_t)r * 64 + c4);
        }
#pragma unroll
        for (int c = 0; c < 5; ++c) {
            __syncthreads();  // previous compute done; LDS free
#pragma unroll
            for (int q = 0; q < 4; ++q) {
                int f = q * 256 + tid;
                int r = f >> 4, c4 = (f & 15) << 2;
                float4 v = bf2f4(ph[q]);
                AsT[c4 + 0][r] = v.x;
                AsT[c4 + 1][r] = v.y;
                AsT[c4 + 2][r] = v.z;
                AsT[c4 + 3][r] = v.w;
                *reinterpret_cast<float4*>(&Bs[r][c4]) = pbv[q];
            }
            if (c < 4) {  // prefetch chunk c+1 while computing chunk c
                const unsigned short* An = AGGh + (size_t)c * 64;   // rel c
                const float* Bn = B1 + (size_t)c * 4096;
#pragma unroll
                for (int q = 0; q < 4; ++q) {
                    int f = q * 256 + tid;
                    int r = f >> 4, c4 = (f & 15) << 2;
                    int vr = row0 + r;
                    ph[q] = make_ushort4(0, 0, 0, 0);
                    if (vr < N)
                        ph[q] = *reinterpret_cast<const ushort4*>(
                            An + (size_t)vr * 256 + c4);
                    pbv[q] = *reinterpret_cast<const float4*>(Bn + (size_t)r * 64 + c4);
                }
            }
            __syncthreads();
#pragma unroll 8
            for (int k = 0; k < 64; ++k) {
                float4 a = *reinterpret_cast<const float4*>(&AsT[k][ty * 4]);
                float4 b = *reinterpret_cast<const float4*>(&Bs[k][tx * 4]);
                acc[0][0] += a.x * b.x; acc[0][1] += a.x * b.y; acc[0][2] += a.x * b.z; acc[0][3] += a.x * b.w;
                acc[1][0] += a.y * b.x; acc[1][1] += a.y * b.y; acc[1][2] += a.y * b.z; acc[1][3] += a.y * b.w;
                acc[2][0] += a.z * b.x; acc[2][1] += a.z * b.y; acc[2][2] += a.z * b.z; acc[2][3] += a.z * b.w;
                acc[3][0] += a.w * b.x; acc[3][1] += a.w * b.y; acc[3][2] += a.w * b.z; acc[3][3] += a.w * b.w;
            }
        }
    } else {
        // single chunk: A = AGGf fp32, B = B0
#pragma unroll
        for (int q = 0; q < 4; ++q) {
            int f = q * 256 + tid;
            int r = f >> 4, c4 = (f & 15) << 2;
            int vr = row0 + r;
            float4 v = make_float4(0.f, 0.f, 0.f, 0.f);
            if (vr < N) v = *reinterpret_cast<const float4*>(AGGf + (size_t)vr * 64 + c4);
            AsT[c4 + 0][r] = v.x;
            AsT[c4 + 1][r] = v.y;
            AsT[c4 + 2][r] = v.z;
            AsT[c4 + 3][r] = v.w;
            *reinterpret_cast<float4*>(&Bs[r][c4]) =
                *reinterpret_cast<const float4*>(B0 + (size_t)r * 64 + c4);
        }
        __syncthreads();
#pragma unroll 8
        for (int k = 0; k < 64; ++k) {
            float4 a = *reinterpret_cast<const float4*>(&AsT[k][ty * 4]);
            float4 b = *reinterpret_cast<const float4*>(&Bs[k][tx * 4]);
            acc[0][0] += a.x * b.x; acc[0][1] += a.x * b.y; acc[0][2] += a.x * b.z; acc[0][3] += a.x * b.w;
            acc[1][0] += a.y * b.x; acc[1][1] += a.y * b.y; acc[1][2] += a.y * b.z; acc[1][3] += a.y * b.w;
            acc[2][0] += a.z * b.x; acc[2][1] += a.z * b.y; acc[2][2] += a.z * b.z; acc[2][3] += a.z * b.w;
            acc[3][0] += a.w * b.x; acc[3][1] += a.w * b.y; acc[3][2] += a.w * b.z; acc[3][3] += a.w * b.w;
        }
    }

    const float alpha = (MODE == 1 || MODE == 3) ? alphap[0] : 0.f;

    if (MODE == 3) {
        // g = Xf + alpha*(acc/deg + bias) -> AsT (transposed: AsT[col][row]);
        // outW -> Bs; OUT = g @ outW + bias2 (64 -> 32).
        __syncthreads();  // main k-loop done everywhere before AsT/Bs reuse
#pragma unroll
        for (int i = 0; i < 4; ++i) {
            int vr = row0 + ty * 4 + i;
            float dg = 1.f;
            if (vr < N) dg = fmaxf((float)(rp2[vr * 4 + 4] - rp2[vr * 4]), 1.f);
#pragma unroll
            for (int j = 0; j < 4; ++j) {
                int col = tx * 4 + j;
                float g = 0.f;
                if (vr < N)
                    g = Xf[(size_t)vr * 64 + col] + alpha * (acc[i][j] / dg + bias[col]);
                AsT[col][ty * 4 + i] = g;
            }
        }
        // stage outW (64 x 32) into Bs[:][0..31]
#pragma unroll
        for (int t = 0; t < 2; ++t) {
            int idx = tid * 2 + t;        // 512 float4s
            int r = idx >> 3;
            int c4 = (idx & 7) << 2;
            *reinterpret_cast<float4*>(&Bs[r][c4]) =
                *reinterpret_cast<const float4*>(B1 + (size_t)r * 32 + c4);
        }
        __syncthreads();
        float acc2[4][2] = {};
#pragma unroll 8
        for (int k = 0; k < 64; ++k) {
            float4 a = *reinterpret_cast<const float4*>(&AsT[k][ty * 4]);  // g[rows][k]
            float b0 = Bs[k][tx * 2];
            float b1 = Bs[k][tx * 2 + 1];
            acc2[0][0] += a.x * b0; acc2[0][1] += a.x * b1;
            acc2[1][0] += a.y * b0; acc2[1][1] += a.y * b1;
            acc2[2][0] += a.z * b0; acc2[2][1] += a.z * b1;
            acc2[3][0] += a.w * b0; acc2[3][1] += a.w * b1;
        }
#pragma unroll
        for (int i = 0; i < 4; ++i) {
            int vr = row0 + ty * 4 + i;
            if (vr >= N) continue;
#pragma unroll
            for (int j = 0; j < 2; ++j) {
                int col = tx * 2 + j;
                OUT[(size_t)vr * 32 + col] = acc2[i][j] + bias2[col];
            }
        }
        return;
    }

#pragma unroll
    for (int i = 0; i < 4; ++i) {
        int vr = row0 + ty * 4 + i;
        if (vr >= N) continue;
        float dg = fmaxf((float)(rp2[vr * 4 + 4] - rp2[vr * 4]), 1.f);
        float4 o;
#pragma unroll
        for (int j = 0; j < 4; ++j) {
            int col = tx * 4 + j;
            float v;
            if (MODE == 0) {
                v = fmaxf(acc[i][j] / dg, 0.f);
            } else {
                v = Xf[(size_t)vr * 64 + col] + alpha * (acc[i][j] / dg + bias[col]);
            }
            OUT[(size_t)vr * 64 + col] = v;
            (&o.x)[j] = v;
        }
        // bf16 shadow row for the next gather's random reads
        *reinterpret_cast<ushort4*>(OUTb + (size_t)vr * 64 + tx * 4) =
            make_ushort4(f2bf(o.x), f2bf(o.y), f2bf(o.z), f2bf(o.w));
    }
}

extern "C" void kernel_launch(void* const* d_in, const int* in_sizes, int n_in,
                              void* d_out, int out_size, void* d_ws, size_t ws_size,
                              hipStream_t stream) {
    const float* x      = (const float*)d_in[0];
    const int*   ei     = (const int*)d_in[1];
    const int*   et     = (const int*)d_in[2];
    const float* ew     = (const float*)d_in[3];
    const float* W1     = (const float*)d_in[4];
    const float* W01    = (const float*)d_in[5];
    const float* alpha1 = (const float*)d_in[6];
    const float* projW1 = (const float*)d_in[7];
    const float* projb1 = (const float*)d_in[8];
    const float* W2     = (const float*)d_in[9];
    const float* W02    = (const float*)d_in[10];
    const float* alpha2 = (const float*)d_in[11];
    const float* projW2 = (const float*)d_in[12];
    const float* projb2 = (const float*)d_in[13];
    const float* outW   = (const float*)d_in[14];
    const float* outb   = (const float*)d_in[15];
    const int N = in_sizes[0] / 64;
    const int E = in_sizes[2];
    const int M = 4 * N;            // (dst, rel) segments
    const int NB = (N + 255) >> 8;  // 256-node dst buckets

    // workspace (4-byte units):
    // bcnt[1024] | bofs[1032] | bcur[1024] | rp2[M+1 (+pad to even)] |
    // pw int2[E] | aggRegion (N*256 floats):
    //     [0,      N*128)  aggH   bf16 N x 256  (relation agg)
    //     [N*128,  N*192)  aggF   fp32 N x 64   (group agg)
    //     [N*192,  N*224)  xb/gb  bf16 N x 64   (shadow: x, then g)
    //     [N*224,  N*256)  hb     bf16 N x 64   (shadow: h)
    //     (recA int2[E] + recB int[E] alias the front during CSR build only)
    // | h[N*64] | g[N*64]
    int*   bcnt = (int*)d_ws;
    int*   bofs = bcnt + 1024;
    int*   bcur = bofs + 1032;
    int*   rp2  = bcur + 1024;
    int2*  pw   = (int2*)(rp2 + ((M + 2) & ~1));
    float* aggRegion = (float*)(pw + E);
    unsigned short* aggH = (unsigned short*)aggRegion;              // bf16 N x 256
    float* aggF = aggRegion + (size_t)N * 128;                      // fp32 N x 64
    unsigned short* xb = (unsigned short*)(aggRegion + (size_t)N * 192);  // also gb
    unsigned short* hb = (unsigned short*)(aggRegion + (size_t)N * 224);
    int2*  recA = (int2*)aggRegion;       // alias: dead once gathers run
    int*   recB = (int*)(recA + E);
    float* hbuf = aggRegion + (size_t)N * 256;
    float* gbuf = hbuf + (size_t)N * 64;

    const int gatherBlocks = (N + 3) / 4;
    const int gemmBlocks = (N + 63) / 64;
    const int pBlocks = (E + PART_EPB - 1) / PART_EPB;

    // ---- CSR build (block-aggregated radix partition, once per call) ----
    hipMemsetAsync(bcnt, 0, 1024 * sizeof(int), stream);
    bucket_hist<<<pBlocks, 256, 0, stream>>>(ei, bcnt, E, NB);
    bucket_scan<<<1, 1024, 0, stream>>>(bcnt, bofs, bcur, NB, E);
    partition<<<pBlocks, 256, 0, stream>>>(ei, et, ew, bcur, recA, recB, E, NB);
    bucket_fill<<<NB, 256, 0, stream>>>(recA, recB, bofs, rp2, pw, N);
    cast_bf16<<<(N * 16 + 255) / 256, 256, 0, stream>>>(x, xb, N * 16);

    // ---- layer 1 ----
    gather_k<1><<<gatherBlocks, 256, 0, stream>>>(xb, rp2, pw, aggH, N);
    node_gemm<0><<<gemmBlocks, 256, 0, stream>>>(nullptr, nullptr, xb, aggH, W01, W1, nullptr, nullptr, nullptr, rp2, hbuf, hb, N);
    gather_k<0><<<gatherBlocks, 256, 0, stream>>>(hb, rp2, pw, aggF, N);
    node_gemm<1><<<gemmBlocks, 256, 0, stream>>>(hbuf, aggF, nullptr, nullptr, projW1, nullptr, projb1, nullptr, alpha1, rp2, gbuf, xb /*gb*/, N);

    // ---- layer 2 ----
    gather_k<1><<<gatherBlocks, 256, 0, stream>>>(xb /*gb*/, rp2, pw, aggH, N);
    node_gemm<0><<<gemmBlocks, 256, 0, stream>>>(nullptr, nullptr, xb, aggH, W02, W2, nullptr, nullptr, nullptr, rp2, hbuf, hb, N);
    gather_k<0><<<gatherBlocks, 256, 0, stream>>>(hb, rp2, pw, aggF, N);
    // group + head fused: writes N x 32 output directly
    node_gemm<3><<<gemmBlocks, 256, 0, stream>>>(hbuf, aggF, nullptr, nullptr, projW2, outW, projb2, outb, alpha2, rp2, (float*)d_out, nullptr, N);
}

// Round 15
// 418.658 us; speedup vs baseline: 1.0199x; 1.0199x over previous
//
#include <hip/hip_runtime.h>

// ---------------------------------------------------------------------------
// MR_GNN: 2x (RGCN + GroupEnhance) + linear head.
// R15 fix: previous round was a call-site arity bug (MODE1/MODE3 launches
// kept a stray nullptr from the R14 13-arg signature; template takes 12).
// Kernel bodies unchanged:
// R13's proven conflict-free row-major As/Bs layout + fp32 chunk-0 A, plus
// ONLY the register-prefetch pipeline in MODE0: chunk c+1's A(bf16)/B(fp32)
// tiles load into individually NAMED registers (no arrays -> no scratch)
// before chunk c's k-loop, written to LDS after it. Staging latency overlaps
// the k-loop (occupancy is grid-limited at ~3 blocks/CU, so within-block
// overlap is the lever). Everything else identical to R13 (400us, 1.9e-6).
// ---------------------------------------------------------------------------

#define PART_EPB 2048  // edges per partition/hist block (256 thr x 8)

// ---- CSR build, pass A1: per-bucket edge counts (bucket = dst >> 8) ----
__global__ __launch_bounds__(256) void bucket_hist(const int* __restrict__ ei,
                                                   int* __restrict__ bcnt,
                                                   int E, int NB) {
    __shared__ int h[1024];
    for (int i = threadIdx.x; i < 1024; i += 256) h[i] = 0;
    __syncthreads();
    int base = blockIdx.x * PART_EPB;
#pragma unroll
    for (int k = 0; k < PART_EPB / 256; ++k) {
        int e = base + k * 256 + threadIdx.x;
        if (e < E) atomicAdd(&h[ei[E + e] >> 8], 1);
    }
    __syncthreads();
    for (int i = threadIdx.x; i < NB; i += 256)
        if (h[i]) atomicAdd(&bcnt[i], h[i]);
}

// ---- pass A-scan: exclusive scan of NB (<=1024) bucket counts ----
__global__ __launch_bounds__(1024) void bucket_scan(const int* __restrict__ bcnt,
                                                    int* __restrict__ bofs,
                                                    int* __restrict__ bcur,
                                                    int NB, int E) {
    __shared__ int lds[1024];
    int tid = threadIdx.x;
    int v = (tid < NB) ? bcnt[tid] : 0;
    lds[tid] = v;
    __syncthreads();
    int acc = v;
    for (int off = 1; off < 1024; off <<= 1) {
        int t = (tid >= off) ? lds[tid - off] : 0;
        __syncthreads();
        acc += t;
        lds[tid] = acc;
        __syncthreads();
    }
    int excl = acc - v;
    if (tid < NB) { bofs[tid] = excl; bcur[tid] = excl; }
    if (tid == 0) bofs[NB] = E;
}

// ---- pass A2: block-aggregated partition into bucket streams ----
__global__ __launch_bounds__(256) void partition(const int* __restrict__ ei,
                                                 const int* __restrict__ et,
                                                 const float* __restrict__ ew,
                                                 int* __restrict__ gcur,
                                                 int2* __restrict__ recA,
                                                 int* __restrict__ recB,
                                                 int E, int NB) {
    __shared__ int hist[1024];
    __shared__ int base[1024];
    const int tid = threadIdx.x;
    const int blockBase = blockIdx.x * PART_EPB;
    for (int i = tid; i < 1024; i += 256) hist[i] = 0;
    __syncthreads();
#pragma unroll
    for (int k = 0; k < PART_EPB / 256; ++k) {
        int e = blockBase + k * 256 + tid;
        if (e < E) atomicAdd(&hist[ei[E + e] >> 8], 1);
    }
    __syncthreads();
    for (int i = tid; i < NB; i += 256) {
        int h = hist[i];
        base[i] = h ? atomicAdd(&gcur[i], h) : 0;
    }
    __syncthreads();
    for (int i = tid; i < 1024; i += 256) hist[i] = 0;  // reuse as run cursor
    __syncthreads();
#pragma unroll
    for (int k = 0; k < PART_EPB / 256; ++k) {
        int e = blockBase + k * 256 + tid;
        if (e >= E) continue;
        int dst = ei[E + e];
        int b = dst >> 8;
        int pos = base[b] + atomicAdd(&hist[b], 1);
        recA[pos] = make_int2(ei[e], __float_as_int(ew[e]));
        recB[pos] = dst * 4 + et[e];
    }
}

// ---- pass B: per-bucket (node,rel) hist + scan in LDS, write rp2 + pw ----
__global__ __launch_bounds__(256) void bucket_fill(
    const int2* __restrict__ recA, const int* __restrict__ recB,
    const int* __restrict__ bofs, int* __restrict__ rp2, int2* __restrict__ pw,
    int N) {
    __shared__ int cnt[1024];
    __shared__ int cur[1024];
    __shared__ int wsum[4];
    const int b = blockIdx.x;
    const int tid = threadIdx.x;
    const int beg = bofs[b], end = bofs[b + 1];
    const int rebase = b << 10;  // base index in (dst*4+rel) space
    for (int j = 0; j < 4; ++j) cnt[tid * 4 + j] = 0;
    __syncthreads();
    for (int i = beg + tid; i < end; i += 256)
        atomicAdd(&cnt[recB[i] - rebase], 1);
    __syncthreads();
    int v[4];
    int s = 0;
#pragma unroll
    for (int j = 0; j < 4; ++j) { v[j] = cnt[tid * 4 + j]; s += v[j]; }
    int lane = tid & 63, wid = tid >> 6;
    int ws = s;
#pragma unroll
    for (int off = 1; off < 64; off <<= 1) {
        int t = __shfl_up(ws, off);
        if (lane >= off) ws += t;
    }
    if (lane == 63) wsum[wid] = ws;
    __syncthreads();
    int wb = 0;
    for (int w = 0; w < wid; ++w) wb += wsum[w];
    int run = beg + wb + ws - s;
#pragma unroll
    for (int j = 0; j < 4; ++j) {
        int idx = rebase + tid * 4 + j;
        if (idx <= 4 * N) rp2[idx] = run;
        cur[tid * 4 + j] = run;
        run += v[j];
    }
    __syncthreads();
    for (int i = beg + tid; i < end; i += 256) {
        int l = recB[i] - rebase;
        int p = atomicAdd(&cur[l], 1);
        pw[p] = recA[i];
    }
}

__device__ __forceinline__ float4 quad_reduce(float4 a) {
#pragma unroll
    for (int off = 16; off < 64; off <<= 1) {
        a.x += __shfl_xor(a.x, off);
        a.y += __shfl_xor(a.y, off);
        a.z += __shfl_xor(a.z, off);
        a.w += __shfl_xor(a.w, off);
    }
    return a;
}

__device__ __forceinline__ void fma4(float4& a, float w, const float4& x) {
    a.x += w * x.x; a.y += w * x.y; a.z += w * x.z; a.w += w * x.w;
}

__device__ __forceinline__ unsigned short f2bf(float f) {
    unsigned u = __float_as_uint(f);
    unsigned r = u + 0x7fffu + ((u >> 16) & 1u);  // round-to-nearest-even
    return (unsigned short)(r >> 16);
}

__device__ __forceinline__ float bf2f(unsigned short h) {
    return __uint_as_float(((unsigned)h) << 16);
}

__device__ __forceinline__ float4 bf2f4(ushort4 h) {
    return make_float4(bf2f(h.x), bf2f(h.y), bf2f(h.z), bf2f(h.w));
}

// ---- fp32 -> bf16 table cast (for x; sequential, ~2us) ----
__global__ __launch_bounds__(256) void cast_bf16(const float* __restrict__ in,
                                                 unsigned short* __restrict__ out,
                                                 int n4) {
    int i = blockIdx.x * 256 + threadIdx.x;
    if (i >= n4) return;
    float4 v = reinterpret_cast<const float4*>(in)[i];
    reinterpret_cast<ushort4*>(out)[i] =
        make_ushort4(f2bf(v.x), f2bf(v.y), f2bf(v.z), f2bf(v.w));
}

// ---------------------------------------------------------------------------
// Unified-range gather (R7 structure; bf16 input table; proven in R13).
// REL=1: masked per-relation accumulators -> bf16 out (ushort N x 256).
// REL=0: 4 chains summed -> fp32 out (float N x 64).
// ---------------------------------------------------------------------------
template <int REL>
__global__ __launch_bounds__(256) void gather_k(
    const unsigned short* __restrict__ Xb, const int* __restrict__ rp2,
    const int2* __restrict__ pw, void* __restrict__ outp, int N) {
    int node = blockIdx.x * 4 + (threadIdx.x >> 6);
    if (node >= N) return;
    int lane = threadIdx.x & 63;
    int q = lane >> 4, m = lane & 15;
    const int4 sv = *reinterpret_cast<const int4*>(rp2 + node * 4);
    const int s0 = sv.x, s1 = sv.y, s2 = sv.z, s3 = sv.w;
    const int s4 = rp2[node * 4 + 4];
    float4 A0 = make_float4(0.f, 0.f, 0.f, 0.f);
    float4 A1 = make_float4(0.f, 0.f, 0.f, 0.f);
    float4 A2 = make_float4(0.f, 0.f, 0.f, 0.f);
    float4 A3 = make_float4(0.f, 0.f, 0.f, 0.f);

    auto accum = [&](int idx, int slot, int2 e, const float4& xv) {
        float w = __int_as_float(e.y);
        if (REL) {
            fma4(A0, (idx < s1) ? w : 0.f, xv);
            fma4(A1, (idx >= s1 && idx < s2) ? w : 0.f, xv);
            fma4(A2, (idx >= s2 && idx < s3) ? w : 0.f, xv);
            fma4(A3, (idx >= s3) ? w : 0.f, xv);
        } else {
            if (slot == 0) fma4(A0, w, xv);
            else if (slot == 1) fma4(A1, w, xv);
            else if (slot == 2) fma4(A2, w, xv);
            else fma4(A3, w, xv);
        }
    };

    int i = s0 + q;
    for (; i + 12 < s4; i += 16) {  // 4 gathers in flight
        int2 e0 = pw[i];
        int2 e1 = pw[i + 4];
        int2 e2 = pw[i + 8];
        int2 e3 = pw[i + 12];
        ushort4 h0 = *reinterpret_cast<const ushort4*>(Xb + (size_t)e0.x * 64 + m * 4);
        ushort4 h1 = *reinterpret_cast<const ushort4*>(Xb + (size_t)e1.x * 64 + m * 4);
        ushort4 h2 = *reinterpret_cast<const ushort4*>(Xb + (size_t)e2.x * 64 + m * 4);
        ushort4 h3 = *reinterpret_cast<const ushort4*>(Xb + (size_t)e3.x * 64 + m * 4);
        accum(i, 0, e0, bf2f4(h0));
        accum(i + 4, 1, e1, bf2f4(h1));
        accum(i + 8, 2, e2, bf2f4(h2));
        accum(i + 12, 3, e3, bf2f4(h3));
    }
    for (; i + 4 < s4; i += 8) {  // 2 in flight
        int2 e0 = pw[i];
        int2 e1 = pw[i + 4];
        ushort4 h0 = *reinterpret_cast<const ushort4*>(Xb + (size_t)e0.x * 64 + m * 4);
        ushort4 h1 = *reinterpret_cast<const ushort4*>(Xb + (size_t)e1.x * 64 + m * 4);
        accum(i, 0, e0, bf2f4(h0));
        accum(i + 4, 1, e1, bf2f4(h1));
    }
    if (i < s4) {
        int2 e0 = pw[i];
        ushort4 h0 = *reinterpret_cast<const ushort4*>(Xb + (size_t)e0.x * 64 + m * 4);
        accum(i, 0, e0, bf2f4(h0));
    }

    if (REL) {
        A0 = quad_reduce(A0);
        A1 = quad_reduce(A1);
        A2 = quad_reduce(A2);
        A3 = quad_reduce(A3);
        float4 o = (q == 0) ? A0 : (q == 1) ? A1 : (q == 2) ? A2 : A3;
        ushort4 h = make_ushort4(f2bf(o.x), f2bf(o.y), f2bf(o.z), f2bf(o.w));
        *reinterpret_cast<ushort4*>((unsigned short*)outp +
                                    (size_t)node * 256 + q * 64 + m * 4) = h;
    } else {
        A0.x += A1.x + A2.x + A3.x;
        A0.y += A1.y + A2.y + A3.y;
        A0.z += A1.z + A2.z + A3.z;
        A0.w += A1.w + A2.w + A3.w;
        A0 = quad_reduce(A0);
        if (q == 0)
            *reinterpret_cast<float4*>((float*)outp + (size_t)node * 64 + m * 4) = A0;
    }
}

// ---------------------------------------------------------------------------
// Node-side tiled GEMM (R13 layout: As[row][col] pad 68, Bs[row][col]; zero
// bank conflicts measured). MODE 0 adds a register-prefetch pipeline over
// the 5 k-chunks with individually named registers (no arrays -> no scratch).
// MODE 0 (rgcn):  OUT = relu((X@B0 + AGGh@B1) / deg)           OUT: N x 64
//                 (AGGh bf16; also writes OUTb = bf16 shadow)
// MODE 1 (group): OUT = X + alpha*((AGG@B0)/deg + bias); +OUTb OUT: N x 64
// MODE 3 (group+head): g = X + alpha*((AGG@B0)/deg + bias);
//                      OUT = g@B1 + bias2                      OUT: N x 32
// ---------------------------------------------------------------------------
template <int MODE>
__global__ __launch_bounds__(256) void node_gemm(
    const float* __restrict__ X, const float* __restrict__ AGG,
    const unsigned short* __restrict__ AGGh, const float* __restrict__ B0,
    const float* __restrict__ B1, const float* __restrict__ bias,
    const float* __restrict__ bias2, const float* __restrict__ alphap,
    const int* __restrict__ rp2, float* __restrict__ OUT,
    unsigned short* __restrict__ OUTb, int N) {
    __shared__ float As[64][68];
    __shared__ float Bs[64][64];
    const int tid = threadIdx.x;
    const int tx = tid & 15, ty = tid >> 4;
    const int row0 = blockIdx.x * 64;
    float acc[4][4] = {};

    // per-q staging coordinates (q = 0..3): f = q*256+tid
    const int r0_ = (0 * 256 + tid) >> 4, c0_ = ((0 * 256 + tid) & 15) << 2;
    const int r1_ = (1 * 256 + tid) >> 4, c1_ = ((1 * 256 + tid) & 15) << 2;
    const int r2_ = (2 * 256 + tid) >> 4, c2_ = ((2 * 256 + tid) & 15) << 2;
    const int r3_ = (3 * 256 + tid) >> 4, c3_ = ((3 * 256 + tid) & 15) << 2;

    if (MODE == 0) {
        // ---- stage chunk 0 directly (A = X fp32, B = B0), as R13 ----
        {
            float4 v0 = make_float4(0.f, 0.f, 0.f, 0.f);
            float4 v1 = v0, v2 = v0, v3 = v0;
            if (row0 + r0_ < N) v0 = *reinterpret_cast<const float4*>(X + (size_t)(row0 + r0_) * 64 + c0_);
            if (row0 + r1_ < N) v1 = *reinterpret_cast<const float4*>(X + (size_t)(row0 + r1_) * 64 + c1_);
            if (row0 + r2_ < N) v2 = *reinterpret_cast<const float4*>(X + (size_t)(row0 + r2_) * 64 + c2_);
            if (row0 + r3_ < N) v3 = *reinterpret_cast<const float4*>(X + (size_t)(row0 + r3_) * 64 + c3_);
            *reinterpret_cast<float4*>(&As[r0_][c0_]) = v0;
            *reinterpret_cast<float4*>(&As[r1_][c1_]) = v1;
            *reinterpret_cast<float4*>(&As[r2_][c2_]) = v2;
            *reinterpret_cast<float4*>(&As[r3_][c3_]) = v3;
            *reinterpret_cast<float4*>(&Bs[r0_][c0_]) = *reinterpret_cast<const float4*>(B0 + (size_t)r0_ * 64 + c0_);
            *reinterpret_cast<float4*>(&Bs[r1_][c1_]) = *reinterpret_cast<const float4*>(B0 + (size_t)r1_ * 64 + c1_);
            *reinterpret_cast<float4*>(&Bs[r2_][c2_]) = *reinterpret_cast<const float4*>(B0 + (size_t)r2_ * 64 + c2_);
            *reinterpret_cast<float4*>(&Bs[r3_][c3_]) = *reinterpret_cast<const float4*>(B0 + (size_t)r3_ * 64 + c3_);
        }
        __syncthreads();

        ushort4 ph0, ph1, ph2, ph3;   // A prefetch (bf16 relation agg)
        float4 pb0, pb1, pb2, pb3;    // B prefetch
#pragma unroll
        for (int c = 0; c < 5; ++c) {
            if (c < 4) {  // issue chunk c+1's global loads before compute
                const unsigned short* An = AGGh + (size_t)c * 64;   // relation c
                const float* Bn = B1 + (size_t)c * 4096;
                ph0 = make_ushort4(0, 0, 0, 0); ph1 = ph0; ph2 = ph0; ph3 = ph0;
                if (row0 + r0_ < N) ph0 = *reinterpret_cast<const ushort4*>(An + (size_t)(row0 + r0_) * 256 + c0_);
                if (row0 + r1_ < N) ph1 = *reinterpret_cast<const ushort4*>(An + (size_t)(row0 + r1_) * 256 + c1_);
                if (row0 + r2_ < N) ph2 = *reinterpret_cast<const ushort4*>(An + (size_t)(row0 + r2_) * 256 + c2_);
                if (row0 + r3_ < N) ph3 = *reinterpret_cast<const ushort4*>(An + (size_t)(row0 + r3_) * 256 + c3_);
                pb0 = *reinterpret_cast<const float4*>(Bn + (size_t)r0_ * 64 + c0_);
                pb1 = *reinterpret_cast<const float4*>(Bn + (size_t)r1_ * 64 + c1_);
                pb2 = *reinterpret_cast<const float4*>(Bn + (size_t)r2_ * 64 + c2_);
                pb3 = *reinterpret_cast<const float4*>(Bn + (size_t)r3_ * 64 + c3_);
            }
            // compute chunk c (R13 k-loop, proven)
#pragma unroll 8
            for (int k = 0; k < 64; ++k) {
                float4 b = *reinterpret_cast<const float4*>(&Bs[k][tx * 4]);
                float a0 = As[ty * 4 + 0][k];
                float a1 = As[ty * 4 + 1][k];
                float a2 = As[ty * 4 + 2][k];
                float a3 = As[ty * 4 + 3][k];
                acc[0][0] += a0 * b.x; acc[0][1] += a0 * b.y; acc[0][2] += a0 * b.z; acc[0][3] += a0 * b.w;
                acc[1][0] += a1 * b.x; acc[1][1] += a1 * b.y; acc[1][2] += a1 * b.z; acc[1][3] += a1 * b.w;
                acc[2][0] += a2 * b.x; acc[2][1] += a2 * b.y; acc[2][2] += a2 * b.z; acc[2][3] += a2 * b.w;
                acc[3][0] += a3 * b.x; acc[3][1] += a3 * b.y; acc[3][2] += a3 * b.z; acc[3][3] += a3 * b.w;
            }
            if (c < 4) {
                __syncthreads();  // all reads of chunk c done
                *reinterpret_cast<float4*>(&As[r0_][c0_]) = bf2f4(ph0);
                *reinterpret_cast<float4*>(&As[r1_][c1_]) = bf2f4(ph1);
                *reinterpret_cast<float4*>(&As[r2_][c2_]) = bf2f4(ph2);
                *reinterpret_cast<float4*>(&As[r3_][c3_]) = bf2f4(ph3);
                *reinterpret_cast<float4*>(&Bs[r0_][c0_]) = pb0;
                *reinterpret_cast<float4*>(&Bs[r1_][c1_]) = pb1;
                *reinterpret_cast<float4*>(&Bs[r2_][c2_]) = pb2;
                *reinterpret_cast<float4*>(&Bs[r3_][c3_]) = pb3;
                __syncthreads();  // chunk c+1 staged
            }
        }
    } else {
        // single chunk: A = AGG fp32, B = B0 (R13 form)
        {
            float4 v0 = make_float4(0.f, 0.f, 0.f, 0.f);
            float4 v1 = v0, v2 = v0, v3 = v0;
            if (row0 + r0_ < N) v0 = *reinterpret_cast<const float4*>(AGG + (size_t)(row0 + r0_) * 64 + c0_);
            if (row0 + r1_ < N) v1 = *reinterpret_cast<const float4*>(AGG + (size_t)(row0 + r1_) * 64 + c1_);
            if (row0 + r2_ < N) v2 = *reinterpret_cast<const float4*>(AGG + (size_t)(row0 + r2_) * 64 + c2_);
            if (row0 + r3_ < N) v3 = *reinterpret_cast<const float4*>(AGG + (size_t)(row0 + r3_) * 64 + c3_);
            *reinterpret_cast<float4*>(&As[r0_][c0_]) = v0;
            *reinterpret_cast<float4*>(&As[r1_][c1_]) = v1;
            *reinterpret_cast<float4*>(&As[r2_][c2_]) = v2;
            *reinterpret_cast<float4*>(&As[r3_][c3_]) = v3;
            *reinterpret_cast<float4*>(&Bs[r0_][c0_]) = *reinterpret_cast<const float4*>(B0 + (size_t)r0_ * 64 + c0_);
            *reinterpret_cast<float4*>(&Bs[r1_][c1_]) = *reinterpret_cast<const float4*>(B0 + (size_t)r1_ * 64 + c1_);
            *reinterpret_cast<float4*>(&Bs[r2_][c2_]) = *reinterpret_cast<const float4*>(B0 + (size_t)r2_ * 64 + c2_);
            *reinterpret_cast<float4*>(&Bs[r3_][c3_]) = *reinterpret_cast<const float4*>(B0 + (size_t)r3_ * 64 + c3_);
        }
        __syncthreads();
#pragma unroll 8
        for (int k = 0; k < 64; ++k) {
            float4 b = *reinterpret_cast<const float4*>(&Bs[k][tx * 4]);
            float a0 = As[ty * 4 + 0][k];
            float a1 = As[ty * 4 + 1][k];
            float a2 = As[ty * 4 + 2][k];
            float a3 = As[ty * 4 + 3][k];
            acc[0][0] += a0 * b.x; acc[0][1] += a0 * b.y; acc[0][2] += a0 * b.z; acc[0][3] += a0 * b.w;
            acc[1][0] += a1 * b.x; acc[1][1] += a1 * b.y; acc[1][2] += a1 * b.z; acc[1][3] += a1 * b.w;
            acc[2][0] += a2 * b.x; acc[2][1] += a2 * b.y; acc[2][2] += a2 * b.z; acc[2][3] += a2 * b.w;
            acc[3][0] += a3 * b.x; acc[3][1] += a3 * b.y; acc[3][2] += a3 * b.z; acc[3][3] += a3 * b.w;
        }
    }

    const float alpha = (MODE == 1 || MODE == 3) ? alphap[0] : 0.f;

    if (MODE == 3) {
        // g = X + alpha*(acc/deg + bias) -> As (LDS); outW -> Bs; then
        // OUT = g @ outW + bias2 (64 -> 32).
        __syncthreads();  // main k-loop done everywhere before As/Bs reuse
#pragma unroll
        for (int i = 0; i < 4; ++i) {
            int vr = row0 + ty * 4 + i;
            float dg = 1.f;
            if (vr < N) dg = fmaxf((float)(rp2[vr * 4 + 4] - rp2[vr * 4]), 1.f);
#pragma unroll
            for (int j = 0; j < 4; ++j) {
                int col = tx * 4 + j;
                float g = 0.f;
                if (vr < N)
                    g = X[(size_t)vr * 64 + col] + alpha * (acc[i][j] / dg + bias[col]);
                As[ty * 4 + i][col] = g;
            }
        }
        // stage outW (64 x 32) into Bs[:][0..31]
#pragma unroll
        for (int t = 0; t < 2; ++t) {
            int idx = tid * 2 + t;        // 512 float4s
            int r = idx >> 3;
            int c4 = (idx & 7) << 2;
            *reinterpret_cast<float4*>(&Bs[r][c4]) =
                *reinterpret_cast<const float4*>(B1 + (size_t)r * 32 + c4);
        }
        __syncthreads();
        float acc2[4][2] = {};
#pragma unroll 8
        for (int k = 0; k < 64; ++k) {
            float b0 = Bs[k][tx * 2];
            float b1 = Bs[k][tx * 2 + 1];
#pragma unroll
            for (int i = 0; i < 4; ++i) {
                float a = As[ty * 4 + i][k];
                acc2[i][0] += a * b0;
                acc2[i][1] += a * b1;
            }
        }
#pragma unroll
        for (int i = 0; i < 4; ++i) {
            int vr = row0 + ty * 4 + i;
            if (vr >= N) continue;
#pragma unroll
            for (int j = 0; j < 2; ++j) {
                int col = tx * 2 + j;
                OUT[(size_t)vr * 32 + col] = acc2[i][j] + bias2[col];
            }
        }
        return;
    }

#pragma unroll
    for (int i = 0; i < 4; ++i) {
        int vr = row0 + ty * 4 + i;
        if (vr >= N) continue;
        float dg = fmaxf((float)(rp2[vr * 4 + 4] - rp2[vr * 4]), 1.f);
        float4 o;
#pragma unroll
        for (int j = 0; j < 4; ++j) {
            int col = tx * 4 + j;
            float v;
            if (MODE == 0) {
                v = fmaxf(acc[i][j] / dg, 0.f);
            } else {
                v = X[(size_t)vr * 64 + col] + alpha * (acc[i][j] / dg + bias[col]);
            }
            OUT[(size_t)vr * 64 + col] = v;
            (&o.x)[j] = v;
        }
        // bf16 shadow row for the next gather's random reads
        *reinterpret_cast<ushort4*>(OUTb + (size_t)vr * 64 + tx * 4) =
            make_ushort4(f2bf(o.x), f2bf(o.y), f2bf(o.z), f2bf(o.w));
    }
}

extern "C" void kernel_launch(void* const* d_in, const int* in_sizes, int n_in,
                              void* d_out, int out_size, void* d_ws, size_t ws_size,
                              hipStream_t stream) {
    const float* x      = (const float*)d_in[0];
    const int*   ei     = (const int*)d_in[1];
    const int*   et     = (const int*)d_in[2];
    const float* ew     = (const float*)d_in[3];
    const float* W1     = (const float*)d_in[4];
    const float* W01    = (const float*)d_in[5];
    const float* alpha1 = (const float*)d_in[6];
    const float* projW1 = (const float*)d_in[7];
    const float* projb1 = (const float*)d_in[8];
    const float* W2     = (const float*)d_in[9];
    const float* W02    = (const float*)d_in[10];
    const float* alpha2 = (const float*)d_in[11];
    const float* projW2 = (const float*)d_in[12];
    const float* projb2 = (const float*)d_in[13];
    const float* outW   = (const float*)d_in[14];
    const float* outb   = (const float*)d_in[15];
    const int N = in_sizes[0] / 64;
    const int E = in_sizes[2];
    const int M = 4 * N;            // (dst, rel) segments
    const int NB = (N + 255) >> 8;  // 256-node dst buckets

    // workspace (4-byte units):
    // bcnt[1024] | bofs[1032] | bcur[1024] | rp2[M+1 (+pad to even)] |
    // pw int2[E] | aggRegion (N*256 floats):
    //     [0,      N*128)  aggH   bf16 N x 256  (relation agg)
    //     [N*128,  N*192)  aggF   fp32 N x 64   (group agg)
    //     [N*192,  N*224)  xb/gb  bf16 N x 64   (shadow: x, then g)
    //     [N*224,  N*256)  hb     bf16 N x 64   (shadow: h)
    //     (recA int2[E] + recB int[E] alias the front during CSR build only)
    // | h[N*64] | g[N*64]
    int*   bcnt = (int*)d_ws;
    int*   bofs = bcnt + 1024;
    int*   bcur = bofs + 1032;
    int*   rp2  = bcur + 1024;
    int2*  pw   = (int2*)(rp2 + ((M + 2) & ~1));
    float* aggRegion = (float*)(pw + E);
    unsigned short* aggH = (unsigned short*)aggRegion;              // bf16 N x 256
    float* aggF = aggRegion + (size_t)N * 128;                      // fp32 N x 64
    unsigned short* xb = (unsigned short*)(aggRegion + (size_t)N * 192);  // also gb
    unsigned short* hb = (unsigned short*)(aggRegion + (size_t)N * 224);
    int2*  recA = (int2*)aggRegion;       // alias: dead once gathers run
    int*   recB = (int*)(recA + E);
    float* hbuf = aggRegion + (size_t)N * 256;
    float* gbuf = hbuf + (size_t)N * 64;

    const int gatherBlocks = (N + 3) / 4;
    const int gemmBlocks = (N + 63) / 64;
    const int pBlocks = (E + PART_EPB - 1) / PART_EPB;

    // ---- CSR build (block-aggregated radix partition, once per call) ----
    hipMemsetAsync(bcnt, 0, 1024 * sizeof(int), stream);
    bucket_hist<<<pBlocks, 256, 0, stream>>>(ei, bcnt, E, NB);
    bucket_scan<<<1, 1024, 0, stream>>>(bcnt, bofs, bcur, NB, E);
    partition<<<pBlocks, 256, 0, stream>>>(ei, et, ew, bcur, recA, recB, E, NB);
    bucket_fill<<<NB, 256, 0, stream>>>(recA, recB, bofs, rp2, pw, N);
    cast_bf16<<<(N * 16 + 255) / 256, 256, 0, stream>>>(x, xb, N * 16);

    // ---- layer 1 ----
    gather_k<1><<<gatherBlocks, 256, 0, stream>>>(xb, rp2, pw, aggH, N);
    node_gemm<0><<<gemmBlocks, 256, 0, stream>>>(x, nullptr, aggH, W01, W1, nullptr, nullptr, nullptr, rp2, hbuf, hb, N);
    gather_k<0><<<gatherBlocks, 256, 0, stream>>>(hb, rp2, pw, aggF, N);
    node_gemm<1><<<gemmBlocks, 256, 0, stream>>>(hbuf, aggF, nullptr, projW1, nullptr, projb1, nullptr, alpha1, rp2, gbuf, xb /*gb*/, N);

    // ---- layer 2 ----
    gather_k<1><<<gatherBlocks, 256, 0, stream>>>(xb /*gb*/, rp2, pw, aggH, N);
    node_gemm<0><<<gemmBlocks, 256, 0, stream>>>(gbuf, nullptr, aggH, W02, W2, nullptr, nullptr, nullptr, rp2, hbuf, hb, N);
    gather_k<0><<<gatherBlocks, 256, 0, stream>>>(hb, rp2, pw, aggF, N);
    // group + head fused: writes N x 32 output directly
    node_gemm<3><<<gemmBlocks, 256, 0, stream>>>(hbuf, aggF, nullptr, projW2, outW, projb2, outb, alpha2, rp2, (float*)d_out, nullptr, N);
}

// Round 16
// 406.350 us; speedup vs baseline: 1.0508x; 1.0303x over previous
//
#include <hip/hip_runtime.h>

// ---------------------------------------------------------------------------
// MR_GNN: 2x (RGCN + GroupEnhance) + linear head.
// R15 -> R16: both ILP attempts on node_gemm<0> regressed (R14 transpose:
// bank conflicts; R15 reg-prefetch: 45->52.7us, VALU 38->32%). Revert to
// R13's exact chunk structure and attack the stall via TLP instead (the
// mechanism that fixed partition in R6): MODE0 moves to 32-row tiles ->
// grid 782->1563 blocks, LDS 33.8->25KB, ~6 blocks/CU resident (was ~3),
// acc[2][4]. Proven row-major float4 staging (0 bank conflicts), no
// prefetch. B re-staged by 2x blocks but is 80KB total = L2-pinned; HBM
// traffic unchanged. MODE1/3 and everything else byte-identical to R13
// (400us, absmax 1.9e-6).
// ---------------------------------------------------------------------------

#define PART_EPB 2048  // edges per partition/hist block (256 thr x 8)

// ---- CSR build, pass A1: per-bucket edge counts (bucket = dst >> 8) ----
__global__ __launch_bounds__(256) void bucket_hist(const int* __restrict__ ei,
                                                   int* __restrict__ bcnt,
                                                   int E, int NB) {
    __shared__ int h[1024];
    for (int i = threadIdx.x; i < 1024; i += 256) h[i] = 0;
    __syncthreads();
    int base = blockIdx.x * PART_EPB;
#pragma unroll
    for (int k = 0; k < PART_EPB / 256; ++k) {
        int e = base + k * 256 + threadIdx.x;
        if (e < E) atomicAdd(&h[ei[E + e] >> 8], 1);
    }
    __syncthreads();
    for (int i = threadIdx.x; i < NB; i += 256)
        if (h[i]) atomicAdd(&bcnt[i], h[i]);
}

// ---- pass A-scan: exclusive scan of NB (<=1024) bucket counts ----
__global__ __launch_bounds__(1024) void bucket_scan(const int* __restrict__ bcnt,
                                                    int* __restrict__ bofs,
                                                    int* __restrict__ bcur,
                                                    int NB, int E) {
    __shared__ int lds[1024];
    int tid = threadIdx.x;
    int v = (tid < NB) ? bcnt[tid] : 0;
    lds[tid] = v;
    __syncthreads();
    int acc = v;
    for (int off = 1; off < 1024; off <<= 1) {
        int t = (tid >= off) ? lds[tid - off] : 0;
        __syncthreads();
        acc += t;
        lds[tid] = acc;
        __syncthreads();
    }
    int excl = acc - v;
    if (tid < NB) { bofs[tid] = excl; bcur[tid] = excl; }
    if (tid == 0) bofs[NB] = E;
}

// ---- pass A2: block-aggregated partition into bucket streams ----
__global__ __launch_bounds__(256) void partition(const int* __restrict__ ei,
                                                 const int* __restrict__ et,
                                                 const float* __restrict__ ew,
                                                 int* __restrict__ gcur,
                                                 int2* __restrict__ recA,
                                                 int* __restrict__ recB,
                                                 int E, int NB) {
    __shared__ int hist[1024];
    __shared__ int base[1024];
    const int tid = threadIdx.x;
    const int blockBase = blockIdx.x * PART_EPB;
    for (int i = tid; i < 1024; i += 256) hist[i] = 0;
    __syncthreads();
#pragma unroll
    for (int k = 0; k < PART_EPB / 256; ++k) {
        int e = blockBase + k * 256 + tid;
        if (e < E) atomicAdd(&hist[ei[E + e] >> 8], 1);
    }
    __syncthreads();
    for (int i = tid; i < NB; i += 256) {
        int h = hist[i];
        base[i] = h ? atomicAdd(&gcur[i], h) : 0;
    }
    __syncthreads();
    for (int i = tid; i < 1024; i += 256) hist[i] = 0;  // reuse as run cursor
    __syncthreads();
#pragma unroll
    for (int k = 0; k < PART_EPB / 256; ++k) {
        int e = blockBase + k * 256 + tid;
        if (e >= E) continue;
        int dst = ei[E + e];
        int b = dst >> 8;
        int pos = base[b] + atomicAdd(&hist[b], 1);
        recA[pos] = make_int2(ei[e], __float_as_int(ew[e]));
        recB[pos] = dst * 4 + et[e];
    }
}

// ---- pass B: per-bucket (node,rel) hist + scan in LDS, write rp2 + pw ----
__global__ __launch_bounds__(256) void bucket_fill(
    const int2* __restrict__ recA, const int* __restrict__ recB,
    const int* __restrict__ bofs, int* __restrict__ rp2, int2* __restrict__ pw,
    int N) {
    __shared__ int cnt[1024];
    __shared__ int cur[1024];
    __shared__ int wsum[4];
    const int b = blockIdx.x;
    const int tid = threadIdx.x;
    const int beg = bofs[b], end = bofs[b + 1];
    const int rebase = b << 10;  // base index in (dst*4+rel) space
    for (int j = 0; j < 4; ++j) cnt[tid * 4 + j] = 0;
    __syncthreads();
    for (int i = beg + tid; i < end; i += 256)
        atomicAdd(&cnt[recB[i] - rebase], 1);
    __syncthreads();
    int v[4];
    int s = 0;
#pragma unroll
    for (int j = 0; j < 4; ++j) { v[j] = cnt[tid * 4 + j]; s += v[j]; }
    int lane = tid & 63, wid = tid >> 6;
    int ws = s;
#pragma unroll
    for (int off = 1; off < 64; off <<= 1) {
        int t = __shfl_up(ws, off);
        if (lane >= off) ws += t;
    }
    if (lane == 63) wsum[wid] = ws;
    __syncthreads();
    int wb = 0;
    for (int w = 0; w < wid; ++w) wb += wsum[w];
    int run = beg + wb + ws - s;
#pragma unroll
    for (int j = 0; j < 4; ++j) {
        int idx = rebase + tid * 4 + j;
        if (idx <= 4 * N) rp2[idx] = run;
        cur[tid * 4 + j] = run;
        run += v[j];
    }
    __syncthreads();
    for (int i = beg + tid; i < end; i += 256) {
        int l = recB[i] - rebase;
        int p = atomicAdd(&cur[l], 1);
        pw[p] = recA[i];
    }
}

__device__ __forceinline__ float4 quad_reduce(float4 a) {
#pragma unroll
    for (int off = 16; off < 64; off <<= 1) {
        a.x += __shfl_xor(a.x, off);
        a.y += __shfl_xor(a.y, off);
        a.z += __shfl_xor(a.z, off);
        a.w += __shfl_xor(a.w, off);
    }
    return a;
}

__device__ __forceinline__ void fma4(float4& a, float w, const float4& x) {
    a.x += w * x.x; a.y += w * x.y; a.z += w * x.z; a.w += w * x.w;
}

__device__ __forceinline__ unsigned short f2bf(float f) {
    unsigned u = __float_as_uint(f);
    unsigned r = u + 0x7fffu + ((u >> 16) & 1u);  // round-to-nearest-even
    return (unsigned short)(r >> 16);
}

__device__ __forceinline__ float bf2f(unsigned short h) {
    return __uint_as_float(((unsigned)h) << 16);
}

__device__ __forceinline__ float4 bf2f4(ushort4 h) {
    return make_float4(bf2f(h.x), bf2f(h.y), bf2f(h.z), bf2f(h.w));
}

// ---- fp32 -> bf16 table cast (for x; sequential, ~2us) ----
__global__ __launch_bounds__(256) void cast_bf16(const float* __restrict__ in,
                                                 unsigned short* __restrict__ out,
                                                 int n4) {
    int i = blockIdx.x * 256 + threadIdx.x;
    if (i >= n4) return;
    float4 v = reinterpret_cast<const float4*>(in)[i];
    reinterpret_cast<ushort4*>(out)[i] =
        make_ushort4(f2bf(v.x), f2bf(v.y), f2bf(v.z), f2bf(v.w));
}

// ---------------------------------------------------------------------------
// Unified-range gather (R7 structure; bf16 input table; proven in R13).
// REL=1: masked per-relation accumulators -> bf16 out (ushort N x 256).
// REL=0: 4 chains summed -> fp32 out (float N x 64).
// ---------------------------------------------------------------------------
template <int REL>
__global__ __launch_bounds__(256) void gather_k(
    const unsigned short* __restrict__ Xb, const int* __restrict__ rp2,
    const int2* __restrict__ pw, void* __restrict__ outp, int N) {
    int node = blockIdx.x * 4 + (threadIdx.x >> 6);
    if (node >= N) return;
    int lane = threadIdx.x & 63;
    int q = lane >> 4, m = lane & 15;
    const int4 sv = *reinterpret_cast<const int4*>(rp2 + node * 4);
    const int s0 = sv.x, s1 = sv.y, s2 = sv.z, s3 = sv.w;
    const int s4 = rp2[node * 4 + 4];
    float4 A0 = make_float4(0.f, 0.f, 0.f, 0.f);
    float4 A1 = make_float4(0.f, 0.f, 0.f, 0.f);
    float4 A2 = make_float4(0.f, 0.f, 0.f, 0.f);
    float4 A3 = make_float4(0.f, 0.f, 0.f, 0.f);

    auto accum = [&](int idx, int slot, int2 e, const float4& xv) {
        float w = __int_as_float(e.y);
        if (REL) {
            fma4(A0, (idx < s1) ? w : 0.f, xv);
            fma4(A1, (idx >= s1 && idx < s2) ? w : 0.f, xv);
            fma4(A2, (idx >= s2 && idx < s3) ? w : 0.f, xv);
            fma4(A3, (idx >= s3) ? w : 0.f, xv);
        } else {
            if (slot == 0) fma4(A0, w, xv);
            else if (slot == 1) fma4(A1, w, xv);
            else if (slot == 2) fma4(A2, w, xv);
            else fma4(A3, w, xv);
        }
    };

    int i = s0 + q;
    for (; i + 12 < s4; i += 16) {  // 4 gathers in flight
        int2 e0 = pw[i];
        int2 e1 = pw[i + 4];
        int2 e2 = pw[i + 8];
        int2 e3 = pw[i + 12];
        ushort4 h0 = *reinterpret_cast<const ushort4*>(Xb + (size_t)e0.x * 64 + m * 4);
        ushort4 h1 = *reinterpret_cast<const ushort4*>(Xb + (size_t)e1.x * 64 + m * 4);
        ushort4 h2 = *reinterpret_cast<const ushort4*>(Xb + (size_t)e2.x * 64 + m * 4);
        ushort4 h3 = *reinterpret_cast<const ushort4*>(Xb + (size_t)e3.x * 64 + m * 4);
        accum(i, 0, e0, bf2f4(h0));
        accum(i + 4, 1, e1, bf2f4(h1));
        accum(i + 8, 2, e2, bf2f4(h2));
        accum(i + 12, 3, e3, bf2f4(h3));
    }
    for (; i + 4 < s4; i += 8) {  // 2 in flight
        int2 e0 = pw[i];
        int2 e1 = pw[i + 4];
        ushort4 h0 = *reinterpret_cast<const ushort4*>(Xb + (size_t)e0.x * 64 + m * 4);
        ushort4 h1 = *reinterpret_cast<const ushort4*>(Xb + (size_t)e1.x * 64 + m * 4);
        accum(i, 0, e0, bf2f4(h0));
        accum(i + 4, 1, e1, bf2f4(h1));
    }
    if (i < s4) {
        int2 e0 = pw[i];
        ushort4 h0 = *reinterpret_cast<const ushort4*>(Xb + (size_t)e0.x * 64 + m * 4);
        accum(i, 0, e0, bf2f4(h0));
    }

    if (REL) {
        A0 = quad_reduce(A0);
        A1 = quad_reduce(A1);
        A2 = quad_reduce(A2);
        A3 = quad_reduce(A3);
        float4 o = (q == 0) ? A0 : (q == 1) ? A1 : (q == 2) ? A2 : A3;
        ushort4 h = make_ushort4(f2bf(o.x), f2bf(o.y), f2bf(o.z), f2bf(o.w));
        *reinterpret_cast<ushort4*>((unsigned short*)outp +
                                    (size_t)node * 256 + q * 64 + m * 4) = h;
    } else {
        A0.x += A1.x + A2.x + A3.x;
        A0.y += A1.y + A2.y + A3.y;
        A0.z += A1.z + A2.z + A3.z;
        A0.w += A1.w + A2.w + A3.w;
        A0 = quad_reduce(A0);
        if (q == 0)
            *reinterpret_cast<float4*>((float*)outp + (size_t)node * 64 + m * 4) = A0;
    }
}

// ---------------------------------------------------------------------------
// Node-side tiled GEMM, R13 structure (row-major As/Bs staging, 0 bank
// conflicts). MODE 0 uses BM=32 row tiles (2x grid, ~6 blocks/CU) with
// acc[2][4]; MODE 1/3 keep BM=64, acc[4][4].
// MODE 0 (rgcn):  OUT = relu((X@B0 + AGGh@B1) / deg)           OUT: N x 64
//                 (AGGh bf16 N x 256; also writes OUTb bf16 shadow)
// MODE 1 (group): OUT = X + alpha*((AGG@B0)/deg + bias); +OUTb OUT: N x 64
// MODE 3 (group+head): g = X + alpha*((AGG@B0)/deg + bias);
//                      OUT = g@B1 + bias2                      OUT: N x 32
// ---------------------------------------------------------------------------
template <int MODE>
__global__ __launch_bounds__(256) void node_gemm(
    const float* __restrict__ X, const float* __restrict__ AGG,
    const unsigned short* __restrict__ AGGh, const float* __restrict__ B0,
    const float* __restrict__ B1, const float* __restrict__ bias,
    const float* __restrict__ bias2, const float* __restrict__ alphap,
    const int* __restrict__ rp2, float* __restrict__ OUT,
    unsigned short* __restrict__ OUTb, int N) {
    constexpr int BM = (MODE == 0) ? 32 : 64;   // rows per block
    constexpr int NR = BM / 16;                 // rows per thread (2 or 4)
    __shared__ float As[BM][68];
    __shared__ float Bs[64][64];
    const int tid = threadIdx.x;
    const int tx = tid & 15, ty = tid >> 4;
    const int row0 = blockIdx.x * BM;
    float acc[NR][4] = {};

    const int nchunks = (MODE == 0) ? 5 : 1;
    for (int c = 0; c < nchunks; ++c) {
        const float* B;
        if (MODE == 0) B = (c == 0) ? B0 : B1 + (size_t)(c - 1) * 64 * 64;
        else           B = B0;
        if (c) __syncthreads();
        // stage B: 64x64 = 1024 float4s, 4 per thread
#pragma unroll
        for (int q = 0; q < 4; ++q) {
            int f = q * 256 + tid;
            int r = f >> 4, c4 = (f & 15) << 2;
            *reinterpret_cast<float4*>(&Bs[r][c4]) =
                *reinterpret_cast<const float4*>(B + (size_t)r * 64 + c4);
        }
        // stage A: BM x 64 = BM*16 float4s, BM/16 per thread
#pragma unroll
        for (int q = 0; q < BM / 16; ++q) {
            int f = q * 256 + tid;
            int r = f >> 4, c4 = (f & 15) << 2;
            int vr = row0 + r;
            float4 v = make_float4(0.f, 0.f, 0.f, 0.f);
            if (MODE == 0 && c > 0) {
                if (vr < N) {
                    ushort4 hv = *reinterpret_cast<const ushort4*>(
                        AGGh + (size_t)vr * 256 + (c - 1) * 64 + c4);
                    v = bf2f4(hv);
                }
            } else {
                const float* A = (MODE == 0) ? X : AGG;
                if (vr < N) v = *reinterpret_cast<const float4*>(A + (size_t)vr * 64 + c4);
            }
            *reinterpret_cast<float4*>(&As[r][c4]) = v;
        }
        __syncthreads();
#pragma unroll 8
        for (int k = 0; k < 64; ++k) {
            float4 b = *reinterpret_cast<const float4*>(&Bs[k][tx * 4]);
#pragma unroll
            for (int i = 0; i < NR; ++i) {
                float a = As[ty * NR + i][k];
                acc[i][0] += a * b.x;
                acc[i][1] += a * b.y;
                acc[i][2] += a * b.z;
                acc[i][3] += a * b.w;
            }
        }
    }

    const float alpha = (MODE == 1 || MODE == 3) ? alphap[0] : 0.f;

    if (MODE == 3) {
        // g = X + alpha*(acc/deg + bias) -> As (LDS); outW -> Bs; then
        // OUT = g @ outW + bias2 (64 -> 32).
        __syncthreads();  // main k-loop done everywhere before As/Bs reuse
#pragma unroll
        for (int i = 0; i < 4; ++i) {
            int vr = row0 + ty * 4 + i;
            float dg = 1.f;
            if (vr < N) dg = fmaxf((float)(rp2[vr * 4 + 4] - rp2[vr * 4]), 1.f);
#pragma unroll
            for (int j = 0; j < 4; ++j) {
                int col = tx * 4 + j;
                float g = 0.f;
                if (vr < N)
                    g = X[(size_t)vr * 64 + col] + alpha * (acc[i][j] / dg + bias[col]);
                As[ty * 4 + i][col] = g;
            }
        }
        // stage outW (64 x 32) into Bs[:][0..31]
#pragma unroll
        for (int t = 0; t < 2; ++t) {
            int idx = tid * 2 + t;        // 512 float4s
            int r = idx >> 3;
            int c4 = (idx & 7) << 2;
            *reinterpret_cast<float4*>(&Bs[r][c4]) =
                *reinterpret_cast<const float4*>(B1 + (size_t)r * 32 + c4);
        }
        __syncthreads();
        float acc2[4][2] = {};
#pragma unroll 8
        for (int k = 0; k < 64; ++k) {
            float b0 = Bs[k][tx * 2];
            float b1 = Bs[k][tx * 2 + 1];
#pragma unroll
            for (int i = 0; i < 4; ++i) {
                float a = As[ty * 4 + i][k];
                acc2[i][0] += a * b0;
                acc2[i][1] += a * b1;
            }
        }
#pragma unroll
        for (int i = 0; i < 4; ++i) {
            int vr = row0 + ty * 4 + i;
            if (vr >= N) continue;
#pragma unroll
            for (int j = 0; j < 2; ++j) {
                int col = tx * 2 + j;
                OUT[(size_t)vr * 32 + col] = acc2[i][j] + bias2[col];
            }
        }
        return;
    }

#pragma unroll
    for (int i = 0; i < NR; ++i) {
        int vr = row0 + ty * NR + i;
        if (vr >= N) continue;
        float dg = fmaxf((float)(rp2[vr * 4 + 4] - rp2[vr * 4]), 1.f);
        float4 o;
#pragma unroll
        for (int j = 0; j < 4; ++j) {
            int col = tx * 4 + j;
            float v;
            if (MODE == 0) {
                v = fmaxf(acc[i][j] / dg, 0.f);
            } else {
                v = X[(size_t)vr * 64 + col] + alpha * (acc[i][j] / dg + bias[col]);
            }
            OUT[(size_t)vr * 64 + col] = v;
            (&o.x)[j] = v;
        }
        // bf16 shadow row for the next gather's random reads
        *reinterpret_cast<ushort4*>(OUTb + (size_t)vr * 64 + tx * 4) =
            make_ushort4(f2bf(o.x), f2bf(o.y), f2bf(o.z), f2bf(o.w));
    }
}

extern "C" void kernel_launch(void* const* d_in, const int* in_sizes, int n_in,
                              void* d_out, int out_size, void* d_ws, size_t ws_size,
                              hipStream_t stream) {
    const float* x      = (const float*)d_in[0];
    const int*   ei     = (const int*)d_in[1];
    const int*   et     = (const int*)d_in[2];
    const float* ew     = (const float*)d_in[3];
    const float* W1     = (const float*)d_in[4];
    const float* W01    = (const float*)d_in[5];
    const float* alpha1 = (const float*)d_in[6];
    const float* projW1 = (const float*)d_in[7];
    const float* projb1 = (const float*)d_in[8];
    const float* W2     = (const float*)d_in[9];
    const float* W02    = (const float*)d_in[10];
    const float* alpha2 = (const float*)d_in[11];
    const float* projW2 = (const float*)d_in[12];
    const float* projb2 = (const float*)d_in[13];
    const float* outW   = (const float*)d_in[14];
    const float* outb   = (const float*)d_in[15];
    const int N = in_sizes[0] / 64;
    const int E = in_sizes[2];
    const int M = 4 * N;            // (dst, rel) segments
    const int NB = (N + 255) >> 8;  // 256-node dst buckets

    // workspace (4-byte units):
    // bcnt[1024] | bofs[1032] | bcur[1024] | rp2[M+1 (+pad to even)] |
    // pw int2[E] | aggRegion (N*256 floats):
    //     [0,      N*128)  aggH   bf16 N x 256  (relation agg)
    //     [N*128,  N*192)  aggF   fp32 N x 64   (group agg)
    //     [N*192,  N*224)  xb/gb  bf16 N x 64   (shadow: x, then g)
    //     [N*224,  N*256)  hb     bf16 N x 64   (shadow: h)
    //     (recA int2[E] + recB int[E] alias the front during CSR build only)
    // | h[N*64] | g[N*64]
    int*   bcnt = (int*)d_ws;
    int*   bofs = bcnt + 1024;
    int*   bcur = bofs + 1032;
    int*   rp2  = bcur + 1024;
    int2*  pw   = (int2*)(rp2 + ((M + 2) & ~1));
    float* aggRegion = (float*)(pw + E);
    unsigned short* aggH = (unsigned short*)aggRegion;              // bf16 N x 256
    float* aggF = aggRegion + (size_t)N * 128;                      // fp32 N x 64
    unsigned short* xb = (unsigned short*)(aggRegion + (size_t)N * 192);  // also gb
    unsigned short* hb = (unsigned short*)(aggRegion + (size_t)N * 224);
    int2*  recA = (int2*)aggRegion;       // alias: dead once gathers run
    int*   recB = (int*)(recA + E);
    float* hbuf = aggRegion + (size_t)N * 256;
    float* gbuf = hbuf + (size_t)N * 64;

    const int gatherBlocks = (N + 3) / 4;
    const int gemm0Blocks = (N + 31) / 32;   // MODE0: 32-row tiles
    const int gemmBlocks = (N + 63) / 64;    // MODE1/3: 64-row tiles
    const int pBlocks = (E + PART_EPB - 1) / PART_EPB;

    // ---- CSR build (block-aggregated radix partition, once per call) ----
    hipMemsetAsync(bcnt, 0, 1024 * sizeof(int), stream);
    bucket_hist<<<pBlocks, 256, 0, stream>>>(ei, bcnt, E, NB);
    bucket_scan<<<1, 1024, 0, stream>>>(bcnt, bofs, bcur, NB, E);
    partition<<<pBlocks, 256, 0, stream>>>(ei, et, ew, bcur, recA, recB, E, NB);
    bucket_fill<<<NB, 256, 0, stream>>>(recA, recB, bofs, rp2, pw, N);
    cast_bf16<<<(N * 16 + 255) / 256, 256, 0, stream>>>(x, xb, N * 16);

    // ---- layer 1 ----
    gather_k<1><<<gatherBlocks, 256, 0, stream>>>(xb, rp2, pw, aggH, N);
    node_gemm<0><<<gemm0Blocks, 256, 0, stream>>>(x, nullptr, aggH, W01, W1, nullptr, nullptr, nullptr, rp2, hbuf, hb, N);
    gather_k<0><<<gatherBlocks, 256, 0, stream>>>(hb, rp2, pw, aggF, N);
    node_gemm<1><<<gemmBlocks, 256, 0, stream>>>(hbuf, aggF, nullptr, projW1, nullptr, projb1, nullptr, alpha1, rp2, gbuf, xb /*gb*/, N);

    // ---- layer 2 ----
    gather_k<1><<<gatherBlocks, 256, 0, stream>>>(xb /*gb*/, rp2, pw, aggH, N);
    node_gemm<0><<<gemm0Blocks, 256, 0, stream>>>(gbuf, nullptr, aggH, W02, W2, nullptr, nullptr, nullptr, rp2, hbuf, hb, N);
    gather_k<0><<<gatherBlocks, 256, 0, stream>>>(hb, rp2, pw, aggF, N);
    // group + head fused: writes N x 32 output directly
    node_gemm<3><<<gemmBlocks, 256, 0, stream>>>(hbuf, aggF, nullptr, projW2, outW, projb2, outb, alpha2, rp2, (float*)d_out, nullptr, N);
}

// Round 17
// 344.729 us; speedup vs baseline: 1.2387x; 1.1788x over previous
//
#include <hip/hip_runtime.h>

// ---------------------------------------------------------------------------
// MR_GNN: 2x (RGCN + GroupEnhance) + linear head.
// R16 -> R17: three vector-GEMM attacks on node_gemm<0> all failed (R14
// transpose: bank conflicts; R15 reg-prefetch: -17%; R16 small tiles: -24%
// despite 2x occupancy) -- the barrier-chunk structure is the stall. Replace
// it with MFMA (Guideline 10): the A-operand is ALREADY bf16 (xb|aggH from
// R12/R13); pack_w casts [W0;W_r] (320x64) to bf16 in B-fragment order once
// per launch (20KB). rgcn_mfma: per wave 16 rows x 64 cols, 10 K-steps x 4
// col-fragments of mfma_f32_16x16x32_bf16, fragments loaded straight from
// global -- ZERO LDS, ZERO barriers. Layouts: A row=lane&15 k=(lane>>4)*8+j;
// B col=lane&15 (pack makes lane's 8 k contiguous); C/D col=lane&15,
// row=(lane>>4)*4+reg (m89-verified). Epilogue /deg + relu + bf16 shadow.
// MODE1/3 GEMMs, gathers, CSR build unchanged from the proven 400us config.
// ---------------------------------------------------------------------------

#define PART_EPB 2048  // edges per partition/hist block (256 thr x 8)

using short8 = __attribute__((ext_vector_type(8))) short;
using f32x4v = __attribute__((ext_vector_type(4))) float;

// ---- CSR build, pass A1: per-bucket edge counts (bucket = dst >> 8) ----
__global__ __launch_bounds__(256) void bucket_hist(const int* __restrict__ ei,
                                                   int* __restrict__ bcnt,
                                                   int E, int NB) {
    __shared__ int h[1024];
    for (int i = threadIdx.x; i < 1024; i += 256) h[i] = 0;
    __syncthreads();
    int base = blockIdx.x * PART_EPB;
#pragma unroll
    for (int k = 0; k < PART_EPB / 256; ++k) {
        int e = base + k * 256 + threadIdx.x;
        if (e < E) atomicAdd(&h[ei[E + e] >> 8], 1);
    }
    __syncthreads();
    for (int i = threadIdx.x; i < NB; i += 256)
        if (h[i]) atomicAdd(&bcnt[i], h[i]);
}

// ---- pass A-scan: exclusive scan of NB (<=1024) bucket counts ----
__global__ __launch_bounds__(1024) void bucket_scan(const int* __restrict__ bcnt,
                                                    int* __restrict__ bofs,
                                                    int* __restrict__ bcur,
                                                    int NB, int E) {
    __shared__ int lds[1024];
    int tid = threadIdx.x;
    int v = (tid < NB) ? bcnt[tid] : 0;
    lds[tid] = v;
    __syncthreads();
    int acc = v;
    for (int off = 1; off < 1024; off <<= 1) {
        int t = (tid >= off) ? lds[tid - off] : 0;
        __syncthreads();
        acc += t;
        lds[tid] = acc;
        __syncthreads();
    }
    int excl = acc - v;
    if (tid < NB) { bofs[tid] = excl; bcur[tid] = excl; }
    if (tid == 0) bofs[NB] = E;
}

// ---- pass A2: block-aggregated partition into bucket streams ----
__global__ __launch_bounds__(256) void partition(const int* __restrict__ ei,
                                                 const int* __restrict__ et,
                                                 const float* __restrict__ ew,
                                                 int* __restrict__ gcur,
                                                 int2* __restrict__ recA,
                                                 int* __restrict__ recB,
                                                 int E, int NB) {
    __shared__ int hist[1024];
    __shared__ int base[1024];
    const int tid = threadIdx.x;
    const int blockBase = blockIdx.x * PART_EPB;
    for (int i = tid; i < 1024; i += 256) hist[i] = 0;
    __syncthreads();
#pragma unroll
    for (int k = 0; k < PART_EPB / 256; ++k) {
        int e = blockBase + k * 256 + tid;
        if (e < E) atomicAdd(&hist[ei[E + e] >> 8], 1);
    }
    __syncthreads();
    for (int i = tid; i < NB; i += 256) {
        int h = hist[i];
        base[i] = h ? atomicAdd(&gcur[i], h) : 0;
    }
    __syncthreads();
    for (int i = tid; i < 1024; i += 256) hist[i] = 0;  // reuse as run cursor
    __syncthreads();
#pragma unroll
    for (int k = 0; k < PART_EPB / 256; ++k) {
        int e = blockBase + k * 256 + tid;
        if (e >= E) continue;
        int dst = ei[E + e];
        int b = dst >> 8;
        int pos = base[b] + atomicAdd(&hist[b], 1);
        recA[pos] = make_int2(ei[e], __float_as_int(ew[e]));
        recB[pos] = dst * 4 + et[e];
    }
}

// ---- pass B: per-bucket (node,rel) hist + scan in LDS, write rp2 + pw ----
__global__ __launch_bounds__(256) void bucket_fill(
    const int2* __restrict__ recA, const int* __restrict__ recB,
    const int* __restrict__ bofs, int* __restrict__ rp2, int2* __restrict__ pw,
    int N) {
    __shared__ int cnt[1024];
    __shared__ int cur[1024];
    __shared__ int wsum[4];
    const int b = blockIdx.x;
    const int tid = threadIdx.x;
    const int beg = bofs[b], end = bofs[b + 1];
    const int rebase = b << 10;  // base index in (dst*4+rel) space
    for (int j = 0; j < 4; ++j) cnt[tid * 4 + j] = 0;
    __syncthreads();
    for (int i = beg + tid; i < end; i += 256)
        atomicAdd(&cnt[recB[i] - rebase], 1);
    __syncthreads();
    int v[4];
    int s = 0;
#pragma unroll
    for (int j = 0; j < 4; ++j) { v[j] = cnt[tid * 4 + j]; s += v[j]; }
    int lane = tid & 63, wid = tid >> 6;
    int ws = s;
#pragma unroll
    for (int off = 1; off < 64; off <<= 1) {
        int t = __shfl_up(ws, off);
        if (lane >= off) ws += t;
    }
    if (lane == 63) wsum[wid] = ws;
    __syncthreads();
    int wb = 0;
    for (int w = 0; w < wid; ++w) wb += wsum[w];
    int run = beg + wb + ws - s;
#pragma unroll
    for (int j = 0; j < 4; ++j) {
        int idx = rebase + tid * 4 + j;
        if (idx <= 4 * N) rp2[idx] = run;
        cur[tid * 4 + j] = run;
        run += v[j];
    }
    __syncthreads();
    for (int i = beg + tid; i < end; i += 256) {
        int l = recB[i] - rebase;
        int p = atomicAdd(&cur[l], 1);
        pw[p] = recA[i];
    }
}

__device__ __forceinline__ float4 quad_reduce(float4 a) {
#pragma unroll
    for (int off = 16; off < 64; off <<= 1) {
        a.x += __shfl_xor(a.x, off);
        a.y += __shfl_xor(a.y, off);
        a.z += __shfl_xor(a.z, off);
        a.w += __shfl_xor(a.w, off);
    }
    return a;
}

__device__ __forceinline__ void fma4(float4& a, float w, const float4& x) {
    a.x += w * x.x; a.y += w * x.y; a.z += w * x.z; a.w += w * x.w;
}

__device__ __forceinline__ unsigned short f2bf(float f) {
    unsigned u = __float_as_uint(f);
    unsigned r = u + 0x7fffu + ((u >> 16) & 1u);  // round-to-nearest-even
    return (unsigned short)(r >> 16);
}

__device__ __forceinline__ float bf2f(unsigned short h) {
    return __uint_as_float(((unsigned)h) << 16);
}

__device__ __forceinline__ float4 bf2f4(ushort4 h) {
    return make_float4(bf2f(h.x), bf2f(h.y), bf2f(h.z), bf2f(h.w));
}

// ---- fp32 -> bf16 table cast (for x; sequential, ~2us) ----
__global__ __launch_bounds__(256) void cast_bf16(const float* __restrict__ in,
                                                 unsigned short* __restrict__ out,
                                                 int n4) {
    int i = blockIdx.x * 256 + threadIdx.x;
    if (i >= n4) return;
    float4 v = reinterpret_cast<const float4*>(in)[i];
    reinterpret_cast<ushort4*>(out)[i] =
        make_ushort4(f2bf(v.x), f2bf(v.y), f2bf(v.z), f2bf(v.w));
}

// ---- pack B_cat = [W0 (64x64); Wr (4x64x64)] (K=320 x N=64) into bf16
// MFMA B-fragment order: out[((t*4+n4)*4+kg)*128 + col*8 + j] =
// bf16(B_cat[t*32+kg*8+j][n4*16+col]).  20480 elements. ----
__global__ __launch_bounds__(256) void pack_w(const float* __restrict__ W0,
                                              const float* __restrict__ Wr,
                                              unsigned short* __restrict__ out) {
    int i = blockIdx.x * 256 + threadIdx.x;
    if (i >= 20480) return;
    int j = i & 7, col = (i >> 3) & 15, kg = (i >> 7) & 3, n4 = (i >> 9) & 3, t = i >> 11;
    int k = t * 32 + kg * 8 + j;
    int n = n4 * 16 + col;
    float v = (k < 64) ? W0[k * 64 + n] : Wr[(size_t)(k - 64) * 64 + n];
    out[i] = f2bf(v);
}

// ---------------------------------------------------------------------------
// Unified-range gather (R7 structure; bf16 input table; proven in R13).
// REL=1: masked per-relation accumulators -> bf16 out (ushort N x 256).
// REL=0: 4 chains summed -> fp32 out (float N x 64).
// ---------------------------------------------------------------------------
template <int REL>
__global__ __launch_bounds__(256) void gather_k(
    const unsigned short* __restrict__ Xb, const int* __restrict__ rp2,
    const int2* __restrict__ pw, void* __restrict__ outp, int N) {
    int node = blockIdx.x * 4 + (threadIdx.x >> 6);
    if (node >= N) return;
    int lane = threadIdx.x & 63;
    int q = lane >> 4, m = lane & 15;
    const int4 sv = *reinterpret_cast<const int4*>(rp2 + node * 4);
    const int s0 = sv.x, s1 = sv.y, s2 = sv.z, s3 = sv.w;
    const int s4 = rp2[node * 4 + 4];
    float4 A0 = make_float4(0.f, 0.f, 0.f, 0.f);
    float4 A1 = make_float4(0.f, 0.f, 0.f, 0.f);
    float4 A2 = make_float4(0.f, 0.f, 0.f, 0.f);
    float4 A3 = make_float4(0.f, 0.f, 0.f, 0.f);

    auto accum = [&](int idx, int slot, int2 e, const float4& xv) {
        float w = __int_as_float(e.y);
        if (REL) {
            fma4(A0, (idx < s1) ? w : 0.f, xv);
            fma4(A1, (idx >= s1 && idx < s2) ? w : 0.f, xv);
            fma4(A2, (idx >= s2 && idx < s3) ? w : 0.f, xv);
            fma4(A3, (idx >= s3) ? w : 0.f, xv);
        } else {
            if (slot == 0) fma4(A0, w, xv);
            else if (slot == 1) fma4(A1, w, xv);
            else if (slot == 2) fma4(A2, w, xv);
            else fma4(A3, w, xv);
        }
    };

    int i = s0 + q;
    for (; i + 12 < s4; i += 16) {  // 4 gathers in flight
        int2 e0 = pw[i];
        int2 e1 = pw[i + 4];
        int2 e2 = pw[i + 8];
        int2 e3 = pw[i + 12];
        ushort4 h0 = *reinterpret_cast<const ushort4*>(Xb + (size_t)e0.x * 64 + m * 4);
        ushort4 h1 = *reinterpret_cast<const ushort4*>(Xb + (size_t)e1.x * 64 + m * 4);
        ushort4 h2 = *reinterpret_cast<const ushort4*>(Xb + (size_t)e2.x * 64 + m * 4);
        ushort4 h3 = *reinterpret_cast<const ushort4*>(Xb + (size_t)e3.x * 64 + m * 4);
        accum(i, 0, e0, bf2f4(h0));
        accum(i + 4, 1, e1, bf2f4(h1));
        accum(i + 8, 2, e2, bf2f4(h2));
        accum(i + 12, 3, e3, bf2f4(h3));
    }
    for (; i + 4 < s4; i += 8) {  // 2 in flight
        int2 e0 = pw[i];
        int2 e1 = pw[i + 4];
        ushort4 h0 = *reinterpret_cast<const ushort4*>(Xb + (size_t)e0.x * 64 + m * 4);
        ushort4 h1 = *reinterpret_cast<const ushort4*>(Xb + (size_t)e1.x * 64 + m * 4);
        accum(i, 0, e0, bf2f4(h0));
        accum(i + 4, 1, e1, bf2f4(h1));
    }
    if (i < s4) {
        int2 e0 = pw[i];
        ushort4 h0 = *reinterpret_cast<const ushort4*>(Xb + (size_t)e0.x * 64 + m * 4);
        accum(i, 0, e0, bf2f4(h0));
    }

    if (REL) {
        A0 = quad_reduce(A0);
        A1 = quad_reduce(A1);
        A2 = quad_reduce(A2);
        A3 = quad_reduce(A3);
        float4 o = (q == 0) ? A0 : (q == 1) ? A1 : (q == 2) ? A2 : A3;
        ushort4 h = make_ushort4(f2bf(o.x), f2bf(o.y), f2bf(o.z), f2bf(o.w));
        *reinterpret_cast<ushort4*>((unsigned short*)outp +
                                    (size_t)node * 256 + q * 64 + m * 4) = h;
    } else {
        A0.x += A1.x + A2.x + A3.x;
        A0.y += A1.y + A2.y + A3.y;
        A0.z += A1.z + A2.z + A3.z;
        A0.w += A1.w + A2.w + A3.w;
        A0 = quad_reduce(A0);
        if (q == 0)
            *reinterpret_cast<float4*>((float*)outp + (size_t)node * 64 + m * 4) = A0;
    }
}

// ---------------------------------------------------------------------------
// RGCN transform via MFMA: OUT = relu(([Xb|AGGh] @ Bp) / deg), K = 320.
// Block = 4 waves x 16 rows = 64 rows; per wave: 10 K-steps x 4 col-frags of
// mfma_f32_16x16x32_bf16, fragments straight from global. No LDS/barriers.
// A frag: row = lane&15, k = (lane>>4)*8+j (16B load). B frag: col = lane&15,
// lane's 8 k contiguous by pack_w order. C/D: col=lane&15, row=(lane>>4)*4+r.
// Writes fp32 OUT (N x 64) + bf16 shadow OUTb.
// ---------------------------------------------------------------------------
__global__ __launch_bounds__(256) void rgcn_mfma(
    const unsigned short* __restrict__ Xb, const unsigned short* __restrict__ AGGh,
    const unsigned short* __restrict__ Bp, const int* __restrict__ rp2,
    float* __restrict__ OUT, unsigned short* __restrict__ OUTb, int N) {
    const int tid = threadIdx.x;
    const int w = tid >> 6, l = tid & 63;
    const int lr = l & 15, kg = l >> 4;
    const int rowA = blockIdx.x * 64 + w * 16 + lr;
    const bool okA = rowA < N;
    f32x4v acc0 = {0.f, 0.f, 0.f, 0.f};
    f32x4v acc1 = acc0, acc2 = acc0, acc3 = acc0;
    const unsigned short* xrow = Xb + (size_t)rowA * 64 + kg * 8;
    const unsigned short* arow = AGGh + (size_t)rowA * 256 + kg * 8;
    const unsigned short* bbase = Bp + (size_t)kg * 128 + lr * 8;
#pragma unroll
    for (int t = 0; t < 10; ++t) {
        short8 a = {0, 0, 0, 0, 0, 0, 0, 0};
        if (okA) {
            const unsigned short* pa = (t < 2) ? (xrow + t * 32) : (arow + (t - 2) * 32);
            a = *reinterpret_cast<const short8*>(pa);
        }
        short8 b0 = *reinterpret_cast<const short8*>(bbase + (size_t)t * 2048 + 0 * 512);
        short8 b1 = *reinterpret_cast<const short8*>(bbase + (size_t)t * 2048 + 1 * 512);
        short8 b2 = *reinterpret_cast<const short8*>(bbase + (size_t)t * 2048 + 2 * 512);
        short8 b3 = *reinterpret_cast<const short8*>(bbase + (size_t)t * 2048 + 3 * 512);
        acc0 = __builtin_amdgcn_mfma_f32_16x16x32_bf16(a, b0, acc0, 0, 0, 0);
        acc1 = __builtin_amdgcn_mfma_f32_16x16x32_bf16(a, b1, acc1, 0, 0, 0);
        acc2 = __builtin_amdgcn_mfma_f32_16x16x32_bf16(a, b2, acc2, 0, 0, 0);
        acc3 = __builtin_amdgcn_mfma_f32_16x16x32_bf16(a, b3, acc3, 0, 0, 0);
    }
    const int rbase = blockIdx.x * 64 + w * 16 + kg * 4;
#pragma unroll
    for (int j = 0; j < 4; ++j) {
        int row = rbase + j;
        if (row >= N) continue;
        float dg = fmaxf((float)(rp2[row * 4 + 4] - rp2[row * 4]), 1.f);
        float v0 = fmaxf(acc0[j] / dg, 0.f);
        float v1 = fmaxf(acc1[j] / dg, 0.f);
        float v2 = fmaxf(acc2[j] / dg, 0.f);
        float v3 = fmaxf(acc3[j] / dg, 0.f);
        size_t rb = (size_t)row * 64 + lr;
        OUT[rb + 0]  = v0;
        OUT[rb + 16] = v1;
        OUT[rb + 32] = v2;
        OUT[rb + 48] = v3;
        OUTb[rb + 0]  = f2bf(v0);
        OUTb[rb + 16] = f2bf(v1);
        OUTb[rb + 32] = f2bf(v2);
        OUTb[rb + 48] = f2bf(v3);
    }
}

// ---------------------------------------------------------------------------
// Node-side tiled GEMM (vector; R13/R16-proven). Only MODE 1/3 used now.
// MODE 1 (group): OUT = X + alpha*((AGG@B0)/deg + bias); +OUTb OUT: N x 64
// MODE 3 (group+head): g = X + alpha*((AGG@B0)/deg + bias);
//                      OUT = g@B1 + bias2                      OUT: N x 32
// ---------------------------------------------------------------------------
template <int MODE>
__global__ __launch_bounds__(256) void node_gemm(
    const float* __restrict__ X, const float* __restrict__ AGG,
    const float* __restrict__ B0, const float* __restrict__ B1,
    const float* __restrict__ bias, const float* __restrict__ bias2,
    const float* __restrict__ alphap, const int* __restrict__ rp2,
    float* __restrict__ OUT, unsigned short* __restrict__ OUTb, int N) {
    __shared__ float As[64][68];
    __shared__ float Bs[64][64];
    const int tid = threadIdx.x;
    const int tx = tid & 15, ty = tid >> 4;
    const int row0 = blockIdx.x * 64;
    float acc[4][4] = {};

    // single chunk: A = AGG fp32, B = B0
#pragma unroll
    for (int q = 0; q < 4; ++q) {
        int f = q * 256 + tid;
        int r = f >> 4, c4 = (f & 15) << 2;
        int vr = row0 + r;
        float4 v = make_float4(0.f, 0.f, 0.f, 0.f);
        if (vr < N) v = *reinterpret_cast<const float4*>(AGG + (size_t)vr * 64 + c4);
        *reinterpret_cast<float4*>(&As[r][c4]) = v;
        *reinterpret_cast<float4*>(&Bs[r][c4]) =
            *reinterpret_cast<const float4*>(B0 + (size_t)r * 64 + c4);
    }
    __syncthreads();
#pragma unroll 8
    for (int k = 0; k < 64; ++k) {
        float4 b = *reinterpret_cast<const float4*>(&Bs[k][tx * 4]);
        float a0 = As[ty * 4 + 0][k];
        float a1 = As[ty * 4 + 1][k];
        float a2 = As[ty * 4 + 2][k];
        float a3 = As[ty * 4 + 3][k];
        acc[0][0] += a0 * b.x; acc[0][1] += a0 * b.y; acc[0][2] += a0 * b.z; acc[0][3] += a0 * b.w;
        acc[1][0] += a1 * b.x; acc[1][1] += a1 * b.y; acc[1][2] += a1 * b.z; acc[1][3] += a1 * b.w;
        acc[2][0] += a2 * b.x; acc[2][1] += a2 * b.y; acc[2][2] += a2 * b.z; acc[2][3] += a2 * b.w;
        acc[3][0] += a3 * b.x; acc[3][1] += a3 * b.y; acc[3][2] += a3 * b.z; acc[3][3] += a3 * b.w;
    }

    const float alpha = alphap[0];

    if (MODE == 3) {
        // g = X + alpha*(acc/deg + bias) -> As (LDS); outW -> Bs; then
        // OUT = g @ outW + bias2 (64 -> 32).
        __syncthreads();  // main k-loop done everywhere before As/Bs reuse
#pragma unroll
        for (int i = 0; i < 4; ++i) {
            int vr = row0 + ty * 4 + i;
            float dg = 1.f;
            if (vr < N) dg = fmaxf((float)(rp2[vr * 4 + 4] - rp2[vr * 4]), 1.f);
#pragma unroll
            for (int j = 0; j < 4; ++j) {
                int col = tx * 4 + j;
                float g = 0.f;
                if (vr < N)
                    g = X[(size_t)vr * 64 + col] + alpha * (acc[i][j] / dg + bias[col]);
                As[ty * 4 + i][col] = g;
            }
        }
        // stage outW (64 x 32) into Bs[:][0..31]
#pragma unroll
        for (int t = 0; t < 2; ++t) {
            int idx = tid * 2 + t;        // 512 float4s
            int r = idx >> 3;
            int c4 = (idx & 7) << 2;
            *reinterpret_cast<float4*>(&Bs[r][c4]) =
                *reinterpret_cast<const float4*>(B1 + (size_t)r * 32 + c4);
        }
        __syncthreads();
        float acc2[4][2] = {};
#pragma unroll 8
        for (int k = 0; k < 64; ++k) {
            float b0 = Bs[k][tx * 2];
            float b1 = Bs[k][tx * 2 + 1];
#pragma unroll
            for (int i = 0; i < 4; ++i) {
                float a = As[ty * 4 + i][k];
                acc2[i][0] += a * b0;
                acc2[i][1] += a * b1;
            }
        }
#pragma unroll
        for (int i = 0; i < 4; ++i) {
            int vr = row0 + ty * 4 + i;
            if (vr >= N) continue;
#pragma unroll
            for (int j = 0; j < 2; ++j) {
                int col = tx * 2 + j;
                OUT[(size_t)vr * 32 + col] = acc2[i][j] + bias2[col];
            }
        }
        return;
    }

#pragma unroll
    for (int i = 0; i < 4; ++i) {
        int vr = row0 + ty * 4 + i;
        if (vr >= N) continue;
        float dg = fmaxf((float)(rp2[vr * 4 + 4] - rp2[vr * 4]), 1.f);
        float4 o;
#pragma unroll
        for (int j = 0; j < 4; ++j) {
            int col = tx * 4 + j;
            float v = X[(size_t)vr * 64 + col] + alpha * (acc[i][j] / dg + bias[col]);
            OUT[(size_t)vr * 64 + col] = v;
            (&o.x)[j] = v;
        }
        // bf16 shadow row for the next gather's random reads
        *reinterpret_cast<ushort4*>(OUTb + (size_t)vr * 64 + tx * 4) =
            make_ushort4(f2bf(o.x), f2bf(o.y), f2bf(o.z), f2bf(o.w));
    }
}

extern "C" void kernel_launch(void* const* d_in, const int* in_sizes, int n_in,
                              void* d_out, int out_size, void* d_ws, size_t ws_size,
                              hipStream_t stream) {
    const float* x      = (const float*)d_in[0];
    const int*   ei     = (const int*)d_in[1];
    const int*   et     = (const int*)d_in[2];
    const float* ew     = (const float*)d_in[3];
    const float* W1     = (const float*)d_in[4];
    const float* W01    = (const float*)d_in[5];
    const float* alpha1 = (const float*)d_in[6];
    const float* projW1 = (const float*)d_in[7];
    const float* projb1 = (const float*)d_in[8];
    const float* W2     = (const float*)d_in[9];
    const float* W02    = (const float*)d_in[10];
    const float* alpha2 = (const float*)d_in[11];
    const float* projW2 = (const float*)d_in[12];
    const float* projb2 = (const float*)d_in[13];
    const float* outW   = (const float*)d_in[14];
    const float* outb   = (const float*)d_in[15];
    const int N = in_sizes[0] / 64;
    const int E = in_sizes[2];
    const int M = 4 * N;            // (dst, rel) segments
    const int NB = (N + 255) >> 8;  // 256-node dst buckets

    // workspace (4-byte units):
    // bcnt[1024] | bofs[1032] | bcur[1024] | rp2[M+1 (+pad)] | pw int2[E] |
    // aggRegion (16B-aligned, N*256 floats):
    //     [0,      N*128)  aggH   bf16 N x 256  (relation agg)
    //     [N*128,  N*192)  aggF   fp32 N x 64   (group agg)
    //     [N*192,  N*224)  xb/gb  bf16 N x 64   (shadow: x, then g)
    //     [N*224,  N*256)  hb     bf16 N x 64   (shadow: h)
    //     (recA int2[E] + recB int[E] alias the front during CSR build only)
    // | h[N*64] | g[N*64] | wb1 bf16[20480] | wb2 bf16[20480]
    int*   bcnt = (int*)d_ws;
    int*   bofs = bcnt + 1024;
    int*   bcur = bofs + 1032;
    int*   rp2  = bcur + 1024;
    int2*  pw   = (int2*)(rp2 + ((M + 2) & ~1));
    float* aggRegion = (float*)(((uintptr_t)(pw + E) + 15) & ~(uintptr_t)15);
    unsigned short* aggH = (unsigned short*)aggRegion;              // bf16 N x 256
    float* aggF = aggRegion + (size_t)N * 128;                      // fp32 N x 64
    unsigned short* xb = (unsigned short*)(aggRegion + (size_t)N * 192);  // also gb
    unsigned short* hb = (unsigned short*)(aggRegion + (size_t)N * 224);
    int2*  recA = (int2*)aggRegion;       // alias: dead once gathers run
    int*   recB = (int*)(recA + E);
    float* hbuf = aggRegion + (size_t)N * 256;
    float* gbuf = hbuf + (size_t)N * 64;
    unsigned short* wb1 = (unsigned short*)(gbuf + (size_t)N * 64);  // packed bf16 320x64
    unsigned short* wb2 = wb1 + 20480;

    const int gatherBlocks = (N + 3) / 4;
    const int gemmBlocks = (N + 63) / 64;
    const int pBlocks = (E + PART_EPB - 1) / PART_EPB;

    // ---- CSR build + weight packing (once per call) ----
    hipMemsetAsync(bcnt, 0, 1024 * sizeof(int), stream);
    bucket_hist<<<pBlocks, 256, 0, stream>>>(ei, bcnt, E, NB);
    bucket_scan<<<1, 1024, 0, stream>>>(bcnt, bofs, bcur, NB, E);
    partition<<<pBlocks, 256, 0, stream>>>(ei, et, ew, bcur, recA, recB, E, NB);
    bucket_fill<<<NB, 256, 0, stream>>>(recA, recB, bofs, rp2, pw, N);
    cast_bf16<<<(N * 16 + 255) / 256, 256, 0, stream>>>(x, xb, N * 16);
    pack_w<<<80, 256, 0, stream>>>(W01, W1, wb1);
    pack_w<<<80, 256, 0, stream>>>(W02, W2, wb2);

    // ---- layer 1 ----
    gather_k<1><<<gatherBlocks, 256, 0, stream>>>(xb, rp2, pw, aggH, N);
    rgcn_mfma<<<gemmBlocks, 256, 0, stream>>>(xb, aggH, wb1, rp2, hbuf, hb, N);
    gather_k<0><<<gatherBlocks, 256, 0, stream>>>(hb, rp2, pw, aggF, N);
    node_gemm<1><<<gemmBlocks, 256, 0, stream>>>(hbuf, aggF, projW1, nullptr, projb1, nullptr, alpha1, rp2, gbuf, xb /*gb*/, N);

    // ---- layer 2 ----
    gather_k<1><<<gatherBlocks, 256, 0, stream>>>(xb /*gb*/, rp2, pw, aggH, N);
    rgcn_mfma<<<gemmBlocks, 256, 0, stream>>>(xb /*gb*/, aggH, wb2, rp2, hbuf, hb, N);
    gather_k<0><<<gatherBlocks, 256, 0, stream>>>(hb, rp2, pw, aggF, N);
    // group + head fused: writes N x 32 output directly
    node_gemm<3><<<gemmBlocks, 256, 0, stream>>>(hbuf, aggF, projW2, outW, projb2, outb, alpha2, rp2, (float*)d_out, nullptr, N);
}

// Round 18
// 338.864 us; speedup vs baseline: 1.2601x; 1.0173x over previous
//
#include <hip/hip_runtime.h>

// ---------------------------------------------------------------------------
// MR_GNN: 2x (RGCN + GroupEnhance) + linear head.
// R17 -> R18: MFMA validated on the RGCN transform (406->345us). Extend the
// same recipe to the last vector GEMMs (group layers):
//  - gather_k<0> now emits bf16 agg (write traffic halved),
//  - pack_w64 casts projW (64x64) to B-fragment order (4KB),
//  - group_mfma<HEAD>: 8 mfma_f32_16x16x32_bf16 per wave from global (no
//    LDS/barriers for HEAD=0); epilogue g = X + alpha*(acc/deg + pb) at C/D
//    positions + bf16 shadow. HEAD=1 stages g to LDS in C/D order and reuses
//    the proven MODE3 vector head mini-GEMM (g@outW+ob -> Nx32).
// (agg/deg)@P == (agg@P)/deg, so math is unchanged; agg precision moves to
// bf16 (validated error class, attenuated by alpha/deg).
// Gathers, CSR build, rgcn_mfma unchanged from R17 (344.7us, 5.7e-6).
// ---------------------------------------------------------------------------

#define PART_EPB 2048  // edges per partition/hist block (256 thr x 8)

using short8 = __attribute__((ext_vector_type(8))) short;
using f32x4v = __attribute__((ext_vector_type(4))) float;

// ---- CSR build, pass A1: per-bucket edge counts (bucket = dst >> 8) ----
__global__ __launch_bounds__(256) void bucket_hist(const int* __restrict__ ei,
                                                   int* __restrict__ bcnt,
                                                   int E, int NB) {
    __shared__ int h[1024];
    for (int i = threadIdx.x; i < 1024; i += 256) h[i] = 0;
    __syncthreads();
    int base = blockIdx.x * PART_EPB;
#pragma unroll
    for (int k = 0; k < PART_EPB / 256; ++k) {
        int e = base + k * 256 + threadIdx.x;
        if (e < E) atomicAdd(&h[ei[E + e] >> 8], 1);
    }
    __syncthreads();
    for (int i = threadIdx.x; i < NB; i += 256)
        if (h[i]) atomicAdd(&bcnt[i], h[i]);
}

// ---- pass A-scan: exclusive scan of NB (<=1024) bucket counts ----
__global__ __launch_bounds__(1024) void bucket_scan(const int* __restrict__ bcnt,
                                                    int* __restrict__ bofs,
                                                    int* __restrict__ bcur,
                                                    int NB, int E) {
    __shared__ int lds[1024];
    int tid = threadIdx.x;
    int v = (tid < NB) ? bcnt[tid] : 0;
    lds[tid] = v;
    __syncthreads();
    int acc = v;
    for (int off = 1; off < 1024; off <<= 1) {
        int t = (tid >= off) ? lds[tid - off] : 0;
        __syncthreads();
        acc += t;
        lds[tid] = acc;
        __syncthreads();
    }
    int excl = acc - v;
    if (tid < NB) { bofs[tid] = excl; bcur[tid] = excl; }
    if (tid == 0) bofs[NB] = E;
}

// ---- pass A2: block-aggregated partition into bucket streams ----
__global__ __launch_bounds__(256) void partition(const int* __restrict__ ei,
                                                 const int* __restrict__ et,
                                                 const float* __restrict__ ew,
                                                 int* __restrict__ gcur,
                                                 int2* __restrict__ recA,
                                                 int* __restrict__ recB,
                                                 int E, int NB) {
    __shared__ int hist[1024];
    __shared__ int base[1024];
    const int tid = threadIdx.x;
    const int blockBase = blockIdx.x * PART_EPB;
    for (int i = tid; i < 1024; i += 256) hist[i] = 0;
    __syncthreads();
#pragma unroll
    for (int k = 0; k < PART_EPB / 256; ++k) {
        int e = blockBase + k * 256 + tid;
        if (e < E) atomicAdd(&hist[ei[E + e] >> 8], 1);
    }
    __syncthreads();
    for (int i = tid; i < NB; i += 256) {
        int h = hist[i];
        base[i] = h ? atomicAdd(&gcur[i], h) : 0;
    }
    __syncthreads();
    for (int i = tid; i < 1024; i += 256) hist[i] = 0;  // reuse as run cursor
    __syncthreads();
#pragma unroll
    for (int k = 0; k < PART_EPB / 256; ++k) {
        int e = blockBase + k * 256 + tid;
        if (e >= E) continue;
        int dst = ei[E + e];
        int b = dst >> 8;
        int pos = base[b] + atomicAdd(&hist[b], 1);
        recA[pos] = make_int2(ei[e], __float_as_int(ew[e]));
        recB[pos] = dst * 4 + et[e];
    }
}

// ---- pass B: per-bucket (node,rel) hist + scan in LDS, write rp2 + pw ----
__global__ __launch_bounds__(256) void bucket_fill(
    const int2* __restrict__ recA, const int* __restrict__ recB,
    const int* __restrict__ bofs, int* __restrict__ rp2, int2* __restrict__ pw,
    int N) {
    __shared__ int cnt[1024];
    __shared__ int cur[1024];
    __shared__ int wsum[4];
    const int b = blockIdx.x;
    const int tid = threadIdx.x;
    const int beg = bofs[b], end = bofs[b + 1];
    const int rebase = b << 10;  // base index in (dst*4+rel) space
    for (int j = 0; j < 4; ++j) cnt[tid * 4 + j] = 0;
    __syncthreads();
    for (int i = beg + tid; i < end; i += 256)
        atomicAdd(&cnt[recB[i] - rebase], 1);
    __syncthreads();
    int v[4];
    int s = 0;
#pragma unroll
    for (int j = 0; j < 4; ++j) { v[j] = cnt[tid * 4 + j]; s += v[j]; }
    int lane = tid & 63, wid = tid >> 6;
    int ws = s;
#pragma unroll
    for (int off = 1; off < 64; off <<= 1) {
        int t = __shfl_up(ws, off);
        if (lane >= off) ws += t;
    }
    if (lane == 63) wsum[wid] = ws;
    __syncthreads();
    int wb = 0;
    for (int w = 0; w < wid; ++w) wb += wsum[w];
    int run = beg + wb + ws - s;
#pragma unroll
    for (int j = 0; j < 4; ++j) {
        int idx = rebase + tid * 4 + j;
        if (idx <= 4 * N) rp2[idx] = run;
        cur[tid * 4 + j] = run;
        run += v[j];
    }
    __syncthreads();
    for (int i = beg + tid; i < end; i += 256) {
        int l = recB[i] - rebase;
        int p = atomicAdd(&cur[l], 1);
        pw[p] = recA[i];
    }
}

__device__ __forceinline__ float4 quad_reduce(float4 a) {
#pragma unroll
    for (int off = 16; off < 64; off <<= 1) {
        a.x += __shfl_xor(a.x, off);
        a.y += __shfl_xor(a.y, off);
        a.z += __shfl_xor(a.z, off);
        a.w += __shfl_xor(a.w, off);
    }
    return a;
}

__device__ __forceinline__ void fma4(float4& a, float w, const float4& x) {
    a.x += w * x.x; a.y += w * x.y; a.z += w * x.z; a.w += w * x.w;
}

__device__ __forceinline__ unsigned short f2bf(float f) {
    unsigned u = __float_as_uint(f);
    unsigned r = u + 0x7fffu + ((u >> 16) & 1u);  // round-to-nearest-even
    return (unsigned short)(r >> 16);
}

__device__ __forceinline__ float bf2f(unsigned short h) {
    return __uint_as_float(((unsigned)h) << 16);
}

__device__ __forceinline__ float4 bf2f4(ushort4 h) {
    return make_float4(bf2f(h.x), bf2f(h.y), bf2f(h.z), bf2f(h.w));
}

// ---- fp32 -> bf16 table cast (for x; sequential, ~2us) ----
__global__ __launch_bounds__(256) void cast_bf16(const float* __restrict__ in,
                                                 unsigned short* __restrict__ out,
                                                 int n4) {
    int i = blockIdx.x * 256 + threadIdx.x;
    if (i >= n4) return;
    float4 v = reinterpret_cast<const float4*>(in)[i];
    reinterpret_cast<ushort4*>(out)[i] =
        make_ushort4(f2bf(v.x), f2bf(v.y), f2bf(v.z), f2bf(v.w));
}

// ---- pack B_cat = [W0 (64x64); Wr (4x64x64)] (K=320 x N=64) into bf16
// MFMA B-fragment order: out[((t*4+n4)*4+kg)*128 + col*8 + j] =
// bf16(B_cat[t*32+kg*8+j][n4*16+col]).  20480 elements. ----
__global__ __launch_bounds__(256) void pack_w(const float* __restrict__ W0,
                                              const float* __restrict__ Wr,
                                              unsigned short* __restrict__ out) {
    int i = blockIdx.x * 256 + threadIdx.x;
    if (i >= 20480) return;
    int j = i & 7, col = (i >> 3) & 15, kg = (i >> 7) & 3, n4 = (i >> 9) & 3, t = i >> 11;
    int k = t * 32 + kg * 8 + j;
    int n = n4 * 16 + col;
    float v = (k < 64) ? W0[k * 64 + n] : Wr[(size_t)(k - 64) * 64 + n];
    out[i] = f2bf(v);
}

// ---- same pack for a single 64x64 weight (K=64): 4096 elements ----
__global__ __launch_bounds__(256) void pack_w64(const float* __restrict__ W,
                                                unsigned short* __restrict__ out) {
    int i = blockIdx.x * 256 + threadIdx.x;
    if (i >= 4096) return;
    int j = i & 7, col = (i >> 3) & 15, kg = (i >> 7) & 3, n4 = (i >> 9) & 3, t = i >> 11;
    int k = t * 32 + kg * 8 + j;
    int n = n4 * 16 + col;
    out[i] = f2bf(W[k * 64 + n]);
}

// ---------------------------------------------------------------------------
// Unified-range gather (R7 structure; bf16 input table; proven in R13).
// REL=1: masked per-relation accumulators -> bf16 out (ushort N x 256).
// REL=0: 4 chains summed -> bf16 out (ushort N x 64).
// ---------------------------------------------------------------------------
template <int REL>
__global__ __launch_bounds__(256) void gather_k(
    const unsigned short* __restrict__ Xb, const int* __restrict__ rp2,
    const int2* __restrict__ pw, unsigned short* __restrict__ outp, int N) {
    int node = blockIdx.x * 4 + (threadIdx.x >> 6);
    if (node >= N) return;
    int lane = threadIdx.x & 63;
    int q = lane >> 4, m = lane & 15;
    const int4 sv = *reinterpret_cast<const int4*>(rp2 + node * 4);
    const int s0 = sv.x, s1 = sv.y, s2 = sv.z, s3 = sv.w;
    const int s4 = rp2[node * 4 + 4];
    float4 A0 = make_float4(0.f, 0.f, 0.f, 0.f);
    float4 A1 = make_float4(0.f, 0.f, 0.f, 0.f);
    float4 A2 = make_float4(0.f, 0.f, 0.f, 0.f);
    float4 A3 = make_float4(0.f, 0.f, 0.f, 0.f);

    auto accum = [&](int idx, int slot, int2 e, const float4& xv) {
        float w = __int_as_float(e.y);
        if (REL) {
            fma4(A0, (idx < s1) ? w : 0.f, xv);
            fma4(A1, (idx >= s1 && idx < s2) ? w : 0.f, xv);
            fma4(A2, (idx >= s2 && idx < s3) ? w : 0.f, xv);
            fma4(A3, (idx >= s3) ? w : 0.f, xv);
        } else {
            if (slot == 0) fma4(A0, w, xv);
            else if (slot == 1) fma4(A1, w, xv);
            else if (slot == 2) fma4(A2, w, xv);
            else fma4(A3, w, xv);
        }
    };

    int i = s0 + q;
    for (; i + 12 < s4; i += 16) {  // 4 gathers in flight
        int2 e0 = pw[i];
        int2 e1 = pw[i + 4];
        int2 e2 = pw[i + 8];
        int2 e3 = pw[i + 12];
        ushort4 h0 = *reinterpret_cast<const ushort4*>(Xb + (size_t)e0.x * 64 + m * 4);
        ushort4 h1 = *reinterpret_cast<const ushort4*>(Xb + (size_t)e1.x * 64 + m * 4);
        ushort4 h2 = *reinterpret_cast<const ushort4*>(Xb + (size_t)e2.x * 64 + m * 4);
        ushort4 h3 = *reinterpret_cast<const ushort4*>(Xb + (size_t)e3.x * 64 + m * 4);
        accum(i, 0, e0, bf2f4(h0));
        accum(i + 4, 1, e1, bf2f4(h1));
        accum(i + 8, 2, e2, bf2f4(h2));
        accum(i + 12, 3, e3, bf2f4(h3));
    }
    for (; i + 4 < s4; i += 8) {  // 2 in flight
        int2 e0 = pw[i];
        int2 e1 = pw[i + 4];
        ushort4 h0 = *reinterpret_cast<const ushort4*>(Xb + (size_t)e0.x * 64 + m * 4);
        ushort4 h1 = *reinterpret_cast<const ushort4*>(Xb + (size_t)e1.x * 64 + m * 4);
        accum(i, 0, e0, bf2f4(h0));
        accum(i + 4, 1, e1, bf2f4(h1));
    }
    if (i < s4) {
        int2 e0 = pw[i];
        ushort4 h0 = *reinterpret_cast<const ushort4*>(Xb + (size_t)e0.x * 64 + m * 4);
        accum(i, 0, e0, bf2f4(h0));
    }

    if (REL) {
        A0 = quad_reduce(A0);
        A1 = quad_reduce(A1);
        A2 = quad_reduce(A2);
        A3 = quad_reduce(A3);
        float4 o = (q == 0) ? A0 : (q == 1) ? A1 : (q == 2) ? A2 : A3;
        ushort4 h = make_ushort4(f2bf(o.x), f2bf(o.y), f2bf(o.z), f2bf(o.w));
        *reinterpret_cast<ushort4*>(outp + (size_t)node * 256 + q * 64 + m * 4) = h;
    } else {
        A0.x += A1.x + A2.x + A3.x;
        A0.y += A1.y + A2.y + A3.y;
        A0.z += A1.z + A2.z + A3.z;
        A0.w += A1.w + A2.w + A3.w;
        A0 = quad_reduce(A0);
        if (q == 0) {
            ushort4 h = make_ushort4(f2bf(A0.x), f2bf(A0.y), f2bf(A0.z), f2bf(A0.w));
            *reinterpret_cast<ushort4*>(outp + (size_t)node * 64 + m * 4) = h;
        }
    }
}

// ---------------------------------------------------------------------------
// RGCN transform via MFMA: OUT = relu(([Xb|AGGh] @ Bp) / deg), K = 320.
// (R17, proven.) Block = 4 waves x 16 rows; 10 K-steps x 4 col-frags from
// global; no LDS/barriers. Writes fp32 OUT (N x 64) + bf16 shadow OUTb.
// ---------------------------------------------------------------------------
__global__ __launch_bounds__(256) void rgcn_mfma(
    const unsigned short* __restrict__ Xb, const unsigned short* __restrict__ AGGh,
    const unsigned short* __restrict__ Bp, const int* __restrict__ rp2,
    float* __restrict__ OUT, unsigned short* __restrict__ OUTb, int N) {
    const int tid = threadIdx.x;
    const int w = tid >> 6, l = tid & 63;
    const int lr = l & 15, kg = l >> 4;
    const int rowA = blockIdx.x * 64 + w * 16 + lr;
    const bool okA = rowA < N;
    f32x4v acc0 = {0.f, 0.f, 0.f, 0.f};
    f32x4v acc1 = acc0, acc2 = acc0, acc3 = acc0;
    const unsigned short* xrow = Xb + (size_t)rowA * 64 + kg * 8;
    const unsigned short* arow = AGGh + (size_t)rowA * 256 + kg * 8;
    const unsigned short* bbase = Bp + (size_t)kg * 128 + lr * 8;
#pragma unroll
    for (int t = 0; t < 10; ++t) {
        short8 a = {0, 0, 0, 0, 0, 0, 0, 0};
        if (okA) {
            const unsigned short* pa = (t < 2) ? (xrow + t * 32) : (arow + (t - 2) * 32);
            a = *reinterpret_cast<const short8*>(pa);
        }
        short8 b0 = *reinterpret_cast<const short8*>(bbase + (size_t)t * 2048 + 0 * 512);
        short8 b1 = *reinterpret_cast<const short8*>(bbase + (size_t)t * 2048 + 1 * 512);
        short8 b2 = *reinterpret_cast<const short8*>(bbase + (size_t)t * 2048 + 2 * 512);
        short8 b3 = *reinterpret_cast<const short8*>(bbase + (size_t)t * 2048 + 3 * 512);
        acc0 = __builtin_amdgcn_mfma_f32_16x16x32_bf16(a, b0, acc0, 0, 0, 0);
        acc1 = __builtin_amdgcn_mfma_f32_16x16x32_bf16(a, b1, acc1, 0, 0, 0);
        acc2 = __builtin_amdgcn_mfma_f32_16x16x32_bf16(a, b2, acc2, 0, 0, 0);
        acc3 = __builtin_amdgcn_mfma_f32_16x16x32_bf16(a, b3, acc3, 0, 0, 0);
    }
    const int rbase = blockIdx.x * 64 + w * 16 + kg * 4;
#pragma unroll
    for (int j = 0; j < 4; ++j) {
        int row = rbase + j;
        if (row >= N) continue;
        float dg = fmaxf((float)(rp2[row * 4 + 4] - rp2[row * 4]), 1.f);
        float v0 = fmaxf(acc0[j] / dg, 0.f);
        float v1 = fmaxf(acc1[j] / dg, 0.f);
        float v2 = fmaxf(acc2[j] / dg, 0.f);
        float v3 = fmaxf(acc3[j] / dg, 0.f);
        size_t rb = (size_t)row * 64 + lr;
        OUT[rb + 0]  = v0;
        OUT[rb + 16] = v1;
        OUT[rb + 32] = v2;
        OUT[rb + 48] = v3;
        OUTb[rb + 0]  = f2bf(v0);
        OUTb[rb + 16] = f2bf(v1);
        OUTb[rb + 32] = f2bf(v2);
        OUTb[rb + 48] = f2bf(v3);
    }
}

// ---------------------------------------------------------------------------
// GroupEnhance via MFMA: acc = AGGb @ Pb (K=64: 2 K-steps x 4 col-frags);
// g = X + alpha*(acc/deg + bias). C/D layout: col = lr+16*frag,
// row = rbase + reg (m89-verified).
// HEAD=0: writes g (fp32 OUT N x 64) + bf16 shadow. No LDS/barriers.
// HEAD=1: stages g into LDS in C/D order, then the proven vector head
//         mini-GEMM: OUT = g @ OW + ob (N x 32).
// ---------------------------------------------------------------------------
template <int HEAD>
__global__ __launch_bounds__(256) void group_mfma(
    const float* __restrict__ X, const unsigned short* __restrict__ AGGb,
    const unsigned short* __restrict__ Pb, const float* __restrict__ bias,
    const float* __restrict__ alphap, const int* __restrict__ rp2,
    const float* __restrict__ OW, const float* __restrict__ ob,
    float* __restrict__ OUT, unsigned short* __restrict__ OUTb, int N) {
    __shared__ float Gs[(HEAD ? 64 : 1)][68];
    __shared__ float Ws[(HEAD ? 64 : 1)][32];
    const int tid = threadIdx.x;
    const int w = tid >> 6, l = tid & 63;
    const int lr = l & 15, kg = l >> 4;
    const int rowA = blockIdx.x * 64 + w * 16 + lr;
    const bool okA = rowA < N;
    f32x4v acc0 = {0.f, 0.f, 0.f, 0.f};
    f32x4v acc1 = acc0, acc2 = acc0, acc3 = acc0;
    const unsigned short* arow = AGGb + (size_t)rowA * 64 + kg * 8;
    const unsigned short* bbase = Pb + (size_t)kg * 128 + lr * 8;
#pragma unroll
    for (int t = 0; t < 2; ++t) {
        short8 a = {0, 0, 0, 0, 0, 0, 0, 0};
        if (okA) a = *reinterpret_cast<const short8*>(arow + t * 32);
        short8 b0 = *reinterpret_cast<const short8*>(bbase + (size_t)t * 2048 + 0 * 512);
        short8 b1 = *reinterpret_cast<const short8*>(bbase + (size_t)t * 2048 + 1 * 512);
        short8 b2 = *reinterpret_cast<const short8*>(bbase + (size_t)t * 2048 + 2 * 512);
        short8 b3 = *reinterpret_cast<const short8*>(bbase + (size_t)t * 2048 + 3 * 512);
        acc0 = __builtin_amdgcn_mfma_f32_16x16x32_bf16(a, b0, acc0, 0, 0, 0);
        acc1 = __builtin_amdgcn_mfma_f32_16x16x32_bf16(a, b1, acc1, 0, 0, 0);
        acc2 = __builtin_amdgcn_mfma_f32_16x16x32_bf16(a, b2, acc2, 0, 0, 0);
        acc3 = __builtin_amdgcn_mfma_f32_16x16x32_bf16(a, b3, acc3, 0, 0, 0);
    }
    const float alpha = alphap[0];
    const int rbase = blockIdx.x * 64 + w * 16 + kg * 4;

    if (!HEAD) {
#pragma unroll
        for (int j = 0; j < 4; ++j) {
            int row = rbase + j;
            if (row >= N) continue;
            float dg = fmaxf((float)(rp2[row * 4 + 4] - rp2[row * 4]), 1.f);
            size_t rb = (size_t)row * 64 + lr;
            float v0 = X[rb + 0]  + alpha * (acc0[j] / dg + bias[lr + 0]);
            float v1 = X[rb + 16] + alpha * (acc1[j] / dg + bias[lr + 16]);
            float v2 = X[rb + 32] + alpha * (acc2[j] / dg + bias[lr + 32]);
            float v3 = X[rb + 48] + alpha * (acc3[j] / dg + bias[lr + 48]);
            OUT[rb + 0]  = v0;
            OUT[rb + 16] = v1;
            OUT[rb + 32] = v2;
            OUT[rb + 48] = v3;
            OUTb[rb + 0]  = f2bf(v0);
            OUTb[rb + 16] = f2bf(v1);
            OUTb[rb + 32] = f2bf(v2);
            OUTb[rb + 48] = f2bf(v3);
        }
        return;
    }

    // HEAD: stage g into Gs in C/D order, then vector head mini-GEMM.
#pragma unroll
    for (int j = 0; j < 4; ++j) {
        int row = rbase + j;
        float v0 = 0.f, v1 = 0.f, v2 = 0.f, v3 = 0.f;
        if (row < N) {
            float dg = fmaxf((float)(rp2[row * 4 + 4] - rp2[row * 4]), 1.f);
            size_t rb = (size_t)row * 64 + lr;
            v0 = X[rb + 0]  + alpha * (acc0[j] / dg + bias[lr + 0]);
            v1 = X[rb + 16] + alpha * (acc1[j] / dg + bias[lr + 16]);
            v2 = X[rb + 32] + alpha * (acc2[j] / dg + bias[lr + 32]);
            v3 = X[rb + 48] + alpha * (acc3[j] / dg + bias[lr + 48]);
        }
        int lrow = w * 16 + kg * 4 + j;
        Gs[lrow][lr + 0]  = v0;
        Gs[lrow][lr + 16] = v1;
        Gs[lrow][lr + 32] = v2;
        Gs[lrow][lr + 48] = v3;
    }
    // stage OW (64 x 32): 512 float4s, 2 per thread
#pragma unroll
    for (int t = 0; t < 2; ++t) {
        int idx = tid * 2 + t;
        int r = idx >> 3;
        int c4 = (idx & 7) << 2;
        *reinterpret_cast<float4*>(&Ws[r][c4]) =
            *reinterpret_cast<const float4*>(OW + (size_t)r * 32 + c4);
    }
    __syncthreads();
    const int tx = tid & 15, ty = tid >> 4;
    const int row0 = blockIdx.x * 64;
    float acc2h[4][2] = {};
#pragma unroll 8
    for (int k = 0; k < 64; ++k) {
        float b0 = Ws[k][tx * 2];
        float b1 = Ws[k][tx * 2 + 1];
#pragma unroll
        for (int i = 0; i < 4; ++i) {
            float a = Gs[ty * 4 + i][k];
            acc2h[i][0] += a * b0;
            acc2h[i][1] += a * b1;
        }
    }
#pragma unroll
    for (int i = 0; i < 4; ++i) {
        int vr = row0 + ty * 4 + i;
        if (vr >= N) continue;
#pragma unroll
        for (int j = 0; j < 2; ++j) {
            int col = tx * 2 + j;
            OUT[(size_t)vr * 32 + col] = acc2h[i][j] + ob[col];
        }
    }
}

extern "C" void kernel_launch(void* const* d_in, const int* in_sizes, int n_in,
                              void* d_out, int out_size, void* d_ws, size_t ws_size,
                              hipStream_t stream) {
    const float* x      = (const float*)d_in[0];
    const int*   ei     = (const int*)d_in[1];
    const int*   et     = (const int*)d_in[2];
    const float* ew     = (const float*)d_in[3];
    const float* W1     = (const float*)d_in[4];
    const float* W01    = (const float*)d_in[5];
    const float* alpha1 = (const float*)d_in[6];
    const float* projW1 = (const float*)d_in[7];
    const float* projb1 = (const float*)d_in[8];
    const float* W2     = (const float*)d_in[9];
    const float* W02    = (const float*)d_in[10];
    const float* alpha2 = (const float*)d_in[11];
    const float* projW2 = (const float*)d_in[12];
    const float* projb2 = (const float*)d_in[13];
    const float* outW   = (const float*)d_in[14];
    const float* outb   = (const float*)d_in[15];
    const int N = in_sizes[0] / 64;
    const int E = in_sizes[2];
    const int M = 4 * N;            // (dst, rel) segments
    const int NB = (N + 255) >> 8;  // 256-node dst buckets

    // workspace (4-byte units):
    // bcnt[1024] | bofs[1032] | bcur[1024] | rp2[M+1 (+pad)] | pw int2[E] |
    // aggRegion (16B-aligned, N*256 floats):
    //     [0,      N*128)  aggH   bf16 N x 256  (relation agg)
    //     [N*128,  N*160)  aggFb  bf16 N x 64   (group agg)
    //     [N*192,  N*224)  xb/gb  bf16 N x 64   (shadow: x, then g)
    //     [N*224,  N*256)  hb     bf16 N x 64   (shadow: h)
    //     (recA int2[E] + recB int[E] alias the front during CSR build only)
    // | h[N*64] | g[N*64] | wb1 bf16[20480] | wb2 bf16[20480]
    // | pb1 bf16[4096] | pb2 bf16[4096]
    int*   bcnt = (int*)d_ws;
    int*   bofs = bcnt + 1024;
    int*   bcur = bofs + 1032;
    int*   rp2  = bcur + 1024;
    int2*  pw   = (int2*)(rp2 + ((M + 2) & ~1));
    float* aggRegion = (float*)(((uintptr_t)(pw + E) + 15) & ~(uintptr_t)15);
    unsigned short* aggH = (unsigned short*)aggRegion;              // bf16 N x 256
    unsigned short* aggFb = (unsigned short*)(aggRegion + (size_t)N * 128);  // bf16 N x 64
    unsigned short* xb = (unsigned short*)(aggRegion + (size_t)N * 192);     // also gb
    unsigned short* hb = (unsigned short*)(aggRegion + (size_t)N * 224);
    int2*  recA = (int2*)aggRegion;       // alias: dead once gathers run
    int*   recB = (int*)(recA + E);
    float* hbuf = aggRegion + (size_t)N * 256;
    float* gbuf = hbuf + (size_t)N * 64;
    unsigned short* wb1 = (unsigned short*)(gbuf + (size_t)N * 64);  // packed bf16 320x64
    unsigned short* wb2 = wb1 + 20480;
    unsigned short* pb1 = wb2 + 20480;                               // packed bf16 64x64
    unsigned short* pb2 = pb1 + 4096;

    const int gatherBlocks = (N + 3) / 4;
    const int gemmBlocks = (N + 63) / 64;
    const int pBlocks = (E + PART_EPB - 1) / PART_EPB;

    // ---- CSR build + weight packing (once per call) ----
    hipMemsetAsync(bcnt, 0, 1024 * sizeof(int), stream);
    bucket_hist<<<pBlocks, 256, 0, stream>>>(ei, bcnt, E, NB);
    bucket_scan<<<1, 1024, 0, stream>>>(bcnt, bofs, bcur, NB, E);
    partition<<<pBlocks, 256, 0, stream>>>(ei, et, ew, bcur, recA, recB, E, NB);
    bucket_fill<<<NB, 256, 0, stream>>>(recA, recB, bofs, rp2, pw, N);
    cast_bf16<<<(N * 16 + 255) / 256, 256, 0, stream>>>(x, xb, N * 16);
    pack_w<<<80, 256, 0, stream>>>(W01, W1, wb1);
    pack_w<<<80, 256, 0, stream>>>(W02, W2, wb2);
    pack_w64<<<16, 256, 0, stream>>>(projW1, pb1);
    pack_w64<<<16, 256, 0, stream>>>(projW2, pb2);

    // ---- layer 1 ----
    gather_k<1><<<gatherBlocks, 256, 0, stream>>>(xb, rp2, pw, aggH, N);
    rgcn_mfma<<<gemmBlocks, 256, 0, stream>>>(xb, aggH, wb1, rp2, hbuf, hb, N);
    gather_k<0><<<gatherBlocks, 256, 0, stream>>>(hb, rp2, pw, aggFb, N);
    group_mfma<0><<<gemmBlocks, 256, 0, stream>>>(hbuf, aggFb, pb1, projb1, alpha1, rp2,
                                                  nullptr, nullptr, gbuf, xb /*gb*/, N);

    // ---- layer 2 ----
    gather_k<1><<<gatherBlocks, 256, 0, stream>>>(xb /*gb*/, rp2, pw, aggH, N);
    rgcn_mfma<<<gemmBlocks, 256, 0, stream>>>(xb /*gb*/, aggH, wb2, rp2, hbuf, hb, N);
    gather_k<0><<<gatherBlocks, 256, 0, stream>>>(hb, rp2, pw, aggFb, N);
    // group + head fused: writes N x 32 output directly
    group_mfma<1><<<gemmBlocks, 256, 0, stream>>>(hbuf, aggFb, pb2, projb2, alpha2, rp2,
                                                  outW, outb, (float*)d_out, nullptr, N);
}